// Round 3
// baseline (174.766 us; speedup 1.0000x reference)
//
#include <hip/hip_runtime.h>

// Problem constants: B=32, T=1024, IN=1024, OUT=1024
// M = B*T = 32768, K = IN = 1024, N = OUT = 1024
#define M_DIM 32768
#define N_DIM 1024
#define K_DIM 1024
#define T_DIM 1024
#define B_DIM 32
#define NCHUNK 8
#define CHUNK_T 128   // T_DIM / NCHUNK

typedef unsigned int uint32;
typedef __attribute__((ext_vector_type(8))) short short8;       // 8 bf16 (MFMA A/B frag)
typedef __attribute__((ext_vector_type(8))) unsigned short ushort8v;
typedef __attribute__((ext_vector_type(4))) float floatx4;      // MFMA C/D frag

__device__ __forceinline__ unsigned short f2bf(float f) {
    uint32 u = __float_as_uint(f);
    uint32 r = u + 0x7fffu + ((u >> 16) & 1u);
    return (unsigned short)(r >> 16);
}

__device__ __forceinline__ void async_load16(const void* g, void* s) {
    __builtin_amdgcn_global_load_lds(
        (const __attribute__((address_space(1))) void*)g,
        (__attribute__((address_space(3))) void*)s,
        16, 0, 0);
}

// 8 f32 -> short8 of bf16 via v_cvt_pk_bf16_f32 (RNE, same as f2bf)
__device__ __forceinline__ short8 pk8(float4 a, float4 b) {
    union { short8 s; uint32 d[4]; } u;
    asm("v_cvt_pk_bf16_f32 %0, %1, %2" : "=v"(u.d[0]) : "v"(a.x), "v"(a.y));
    asm("v_cvt_pk_bf16_f32 %0, %1, %2" : "=v"(u.d[1]) : "v"(a.z), "v"(a.w));
    asm("v_cvt_pk_bf16_f32 %0, %1, %2" : "=v"(u.d[2]) : "v"(b.x), "v"(b.y));
    asm("v_cvt_pk_bf16_f32 %0, %1, %2" : "=v"(u.d[3]) : "v"(b.z), "v"(b.w));
    return u.s;
}

// ---------------------------------------------------------------------------
// fp32 -> bf16 cast, 8 elems/thread (16B store)  [W always; A only in fallback]
// ---------------------------------------------------------------------------
__global__ void cast_f32_bf16_x8(const float* __restrict__ src,
                                 unsigned short* __restrict__ dst, int n8) {
    int i = blockIdx.x * blockDim.x + threadIdx.x;
    if (i < n8) {
        const float4* s4 = (const float4*)src;
        float4 v0 = s4[(size_t)i * 2];
        float4 v1 = s4[(size_t)i * 2 + 1];
        ushort8v o;
        o[0] = f2bf(v0.x); o[1] = f2bf(v0.y); o[2] = f2bf(v0.z); o[3] = f2bf(v0.w);
        o[4] = f2bf(v1.x); o[5] = f2bf(v1.y); o[6] = f2bf(v1.z); o[7] = f2bf(v1.w);
        ((ushort8v*)dst)[i] = o;
    }
}

// ---------------------------------------------------------------------------
// MAIN GEMM, cast-fused: A = X in fp32, DMA'd to LDS as f32, converted to
// bf16 with v_cvt_pk_bf16_f32 during the fragment-load phase. B = W in bf16.
//
// 256x256 tile, BK=32, ring-3 LDS (3 x (A-f32 32KB + B-bf16 16KB) = 144KB),
// distance-2 prefetch, 2 phases/tile x 32 tiles = 64 phases, 16 MFMA/phase.
// Ledger: 6 DMA units/tile (A:4 + B:2), issued 3 at p0 / 3 at p1 into ring
// (g+2)%3. One counted vmcnt(6) per tile at p1 (drains tile g+1; tiles g+2's
// 6 units stay in flight). Tail: vmcnt(0) once at g == NT-2. Ring-3 means the
// staged buffer is never concurrently read -> no region-recycling hazards.
// Swizzle: A chunks of 4 f32, pos = c8 ^ (row&7); B chunks of 8 bf16,
// pos = c4 ^ (row&3); sources pre-swizzled, LDS linear (DMA constraint),
// reads apply the same XOR.
// ---------------------------------------------------------------------------
__global__ __launch_bounds__(512, 2) void gemm_f32a(
    const float* __restrict__ X32,          // [M, K] fp32
    const unsigned short* __restrict__ Bw,  // [N, K] bf16
    const float* __restrict__ bias,         // [N]
    unsigned short* __restrict__ outBf) {   // [M, N] bf16
    extern __shared__ __align__(16) char smemc[];   // 147456 B
    // A ring: f32, buf b at smemc + b*32768 ([256][32] f32)
    // B ring: bf16, at smemc + 98304 + b*16384 ([256][32] bf16)

    const int tid  = threadIdx.x;
    const int lane = tid & 63;
    const int wid  = tid >> 6;      // 0..7
    const int l15  = lane & 15;
    const int quad = lane >> 4;
    const int wm   = wid >> 2;      // 0..1  (M half: 128 rows)
    const int wn   = wid & 3;       // 0..3  (N quarter: 64 cols)

    // XCD-aware remap: 512 blocks; xcd owns 16 M-panels, 4 N-tiles each.
    const int L   = blockIdx.y * gridDim.x + blockIdx.x;   // 0..511
    const int xcd = L & 7;
    const int s   = L >> 3;
    const int bn0 = (s & 3) * 256;
    const int bm0 = (xcd * 16 + (s >> 2)) * 256;

#define STAGE_A_U(U, T, PB) do {                                             \
        int row_ = (U) * 64 + (tid >> 3);                                    \
        int sc_  = ((tid & 7) ^ (row_ & 7)) * 4;                             \
        async_load16(X32 + (size_t)(bm0 + row_) * K_DIM + (T) * 32 + sc_,    \
                     (float*)smemc + (PB) * 8192 + ((U) * 64 + wid * 8) * 32); \
    } while (0)
#define STAGE_B_U(U, T, PB) do {                                             \
        int row_ = (U) * 128 + (tid >> 2);                                   \
        int sc_  = ((tid & 3) ^ (row_ & 3)) * 8;                             \
        async_load16(Bw + (size_t)(bn0 + row_) * K_DIM + (T) * 32 + sc_,     \
                     (unsigned short*)(smemc + 98304) + (PB) * 8192 +        \
                         ((U) * 128 + wid * 16) * 32);                       \
    } while (0)

#define LD_A(IH) do {                                                        \
        const float* As_ = (const float*)smemc + pb * 8192;                  \
        _Pragma("unroll") for (int ii = 0; ii < 4; ++ii) {                   \
            int r_ = wm * 128 + (IH) * 64 + ii * 16 + l15;                   \
            int k_ = l15 & 7;                                                \
            int c0_ = quad * 2;                                              \
            float4 F0 = *(const float4*)&As_[r_ * 32 + ((c0_ ^ k_) * 4)];    \
            float4 F1 = *(const float4*)&As_[r_ * 32 + (((c0_ + 1) ^ k_) * 4)]; \
            af[ii] = pk8(F0, F1);                                            \
        } } while (0)
#define LD_B() do {                                                          \
        const unsigned short* Bs_ =                                          \
            (const unsigned short*)(smemc + 98304) + pb * 8192;              \
        _Pragma("unroll") for (int jj = 0; jj < 4; ++jj) {                   \
            int r_ = wn * 64 + jj * 16 + l15;                                \
            bfr[jj] = *(const short8*)&Bs_[r_ * 32 + ((quad ^ (l15 & 3)) * 8)]; \
        } } while (0)
#define MM(IH) do {                                                          \
        __builtin_amdgcn_s_setprio(1);                                       \
        _Pragma("unroll") for (int ii = 0; ii < 4; ++ii)                     \
        _Pragma("unroll") for (int jj = 0; jj < 4; ++jj)                     \
            acc[(IH) * 4 + ii][jj] =                                         \
                __builtin_amdgcn_mfma_f32_16x16x32_bf16(                     \
                    af[ii], bfr[jj], acc[(IH) * 4 + ii][jj], 0, 0, 0);       \
        __builtin_amdgcn_s_setprio(0);                                       \
    } while (0)

#define FENCE  asm volatile("" ::: "memory")
#define BAR    __builtin_amdgcn_s_barrier()
#define LGKM0  asm volatile("s_waitcnt lgkmcnt(0)" ::: "memory")
#define SCHED0 __builtin_amdgcn_sched_barrier(0)

    floatx4 acc[8][4];
#pragma unroll
    for (int i = 0; i < 8; ++i)
#pragma unroll
        for (int j = 0; j < 4; ++j)
            acc[i][j] = (floatx4){0.f, 0.f, 0.f, 0.f};

    short8 af[4];    // current i-half A frags (converted bf16)
    short8 bfr[4];   // all 4 j B frags (loaded p0, reused p1)

    const int NT = K_DIM / 32;   // 32

    // Prologue: tile 0 -> ring 0, tile 1 -> ring 1 (12 units), drain tile 0.
    STAGE_A_U(0, 0, 0); STAGE_A_U(1, 0, 0); STAGE_A_U(2, 0, 0); STAGE_A_U(3, 0, 0);
    STAGE_B_U(0, 0, 0); STAGE_B_U(1, 0, 0);
    STAGE_A_U(0, 1, 1); STAGE_A_U(1, 1, 1); STAGE_A_U(2, 1, 1); STAGE_A_U(3, 1, 1);
    STAGE_B_U(0, 1, 1); STAGE_B_U(1, 1, 1);
    asm volatile("s_waitcnt vmcnt(6)" ::: "memory");
    FENCE; BAR;

    int pb = 0;
    for (int g = 0; g < NT; ++g) {
        const int pn = (pb >= 1) ? pb - 1 : 2;   // (g+2)%3

        // ---- p0: i-half 0 ----
        LD_A(0); LD_B();
        if (g + 2 < NT) { STAGE_A_U(0, g + 2, pn); STAGE_A_U(1, g + 2, pn);
                          STAGE_A_U(2, g + 2, pn); }
        FENCE; BAR; LGKM0; SCHED0;
        MM(0);
        SCHED0; FENCE; BAR;

        // ---- p1: i-half 1 ----
        LD_A(1);
        if (g + 2 < NT) { STAGE_A_U(3, g + 2, pn); STAGE_B_U(0, g + 2, pn);
                          STAGE_B_U(1, g + 2, pn); }
        if (g < NT - 2) {
            asm volatile("s_waitcnt vmcnt(6)" ::: "memory");  // tile g+1 ready
        } else if (g == NT - 2) {
            asm volatile("s_waitcnt vmcnt(0)" ::: "memory");  // tail drain
        }
        FENCE; BAR; LGKM0; SCHED0;
        MM(1);
        SCHED0; FENCE; BAR;

        pb = (pb == 2) ? 0 : pb + 1;
    }
    asm volatile("s_waitcnt vmcnt(0)" ::: "memory");    // safety (no-op)

    // Epilogue: LDS-staged vectorized C store. Per wave private 4KB region;
    // C/D layout col = lane&15, row = quad*4 + reg. 16 x b16 LDS writes ->
    // 2 x b128 reads -> 2 x 16B global stores per i-block per lane.
    float bb[4];
#pragma unroll
    for (int j = 0; j < 4; ++j) bb[j] = bias[bn0 + wn * 64 + j * 16 + l15];
    unsigned short* eb = (unsigned short*)smemc + wid * 2048;
#pragma unroll
    for (int i = 0; i < 8; ++i) {
#pragma unroll
        for (int j = 0; j < 4; ++j)
#pragma unroll
            for (int r = 0; r < 4; ++r)
                eb[(quad * 4 + r) * 64 + j * 16 + l15] = f2bf(acc[i][j][r] + bb[j]);
        asm volatile("s_waitcnt lgkmcnt(0)" ::: "memory");
        short8 v0 = *(const short8*)&eb[lane * 8];         // rows 0..7
        short8 v1 = *(const short8*)&eb[512 + lane * 8];   // rows 8..15
        int rowg = bm0 + wm * 128 + i * 16 + (lane >> 3);
        int colg = bn0 + wn * 64 + (lane & 7) * 8;
        *(short8*)&outBf[(size_t)rowg * N_DIM + colg] = v0;
        *(short8*)&outBf[(size_t)(rowg + 8) * N_DIM + colg] = v1;
    }
#undef STAGE_A_U
#undef STAGE_B_U
#undef LD_A
#undef LD_B
#undef MM
}

// ---------------------------------------------------------------------------
// R2 8-phase bf16 GEMM — fallback if 144KB LDS opt-in fails (needs cast-A).
// ---------------------------------------------------------------------------
__global__ __launch_bounds__(512, 2) void gemm_8phase(
    const unsigned short* __restrict__ A,   // [M, K] bf16
    const unsigned short* __restrict__ Bw,  // [N, K] bf16
    const float* __restrict__ bias,         // [N]
    unsigned short* __restrict__ outBf) {   // [M, N] bf16
    extern __shared__ __align__(16) unsigned short smem[];  // 131072 B

    const int tid  = threadIdx.x;
    const int lane = tid & 63;
    const int wid  = tid >> 6;
    const int l15  = lane & 15;
    const int quad = lane >> 4;
    const int wm   = wid >> 2;
    const int wn   = wid & 3;

    const int L   = blockIdx.y * gridDim.x + blockIdx.x;
    const int xcd = L & 7;
    const int s   = L >> 3;
    const int bn0 = (s & 3) * 256;
    const int bm0 = (xcd * 16 + (s >> 2)) * 256;

    const int t3  = tid >> 3;
    const int sc8 = ((tid & 7) ^ (t3 & 7)) * 8;

#define STAGE_A(IH, T, PB) do {                                              \
        size_t kof_ = (size_t)(T) * 64 + sc8;                                \
        _Pragma("unroll") for (int q_ = 0; q_ < 2; ++q_) {                   \
            int ar_ = q_ * 128 + (IH) * 64 + t3;                             \
            int dr_ = q_ * 128 + (IH) * 64 + wid * 8;                        \
            async_load16(A + (size_t)(bm0 + ar_) * K_DIM + kof_,             \
                         smem + (PB) * 32768 + dr_ * 64);                    \
        } } while (0)
#define STAGE_B(JH, T, PB) do {                                              \
        size_t kof_ = (size_t)(T) * 64 + sc8;                                \
        _Pragma("unroll") for (int q_ = 0; q_ < 2; ++q_) {                   \
            int br_ = (q_ * 2 + (tid >> 8)) * 64 + (JH) * 32 + (t3 & 31);    \
            int dr_ = (q_ * 2 + (wid >> 2)) * 64 + (JH) * 32 + (wid & 3) * 8;\
            async_load16(Bw + (size_t)(bn0 + br_) * K_DIM + kof_,            \
                         smem + (PB) * 32768 + 16384 + dr_ * 64);            \
        } } while (0)
#define LD_A8(IH) do {                                                       \
        const unsigned short* As_ = smem + pb * 32768;                       \
        _Pragma("unroll") for (int ii = 0; ii < 4; ++ii) {                   \
            int r_ = wm * 128 + (IH) * 64 + ii * 16 + l15;                   \
            _Pragma("unroll") for (int ks = 0; ks < 2; ++ks) {               \
                int c_ = ks * 4 + quad;                                      \
                af[ii][ks] = *(const short8*)&As_[r_ * 64 +                  \
                                                 ((c_ ^ (l15 & 7)) * 8)];    \
            } } } while (0)
#define LD_B8(JH) do {                                                       \
        const unsigned short* Bs_ = smem + pb * 32768 + 16384;               \
        _Pragma("unroll") for (int jj = 0; jj < 2; ++jj) {                   \
            int r_ = wn * 64 + ((JH) * 2 + jj) * 16 + l15;                   \
            _Pragma("unroll") for (int ks = 0; ks < 2; ++ks) {               \
                int c_ = ks * 4 + quad;                                      \
                bfr[(JH) * 2 + jj][ks] = *(const short8*)&Bs_[r_ * 64 +      \
                                                 ((c_ ^ (l15 & 7)) * 8)];    \
            } } } while (0)
#define MM8(IH, JH) do {                                                     \
        __builtin_amdgcn_s_setprio(1);                                       \
        _Pragma("unroll") for (int ii = 0; ii < 4; ++ii)                     \
        _Pragma("unroll") for (int jj = 0; jj < 2; ++jj)                     \
        _Pragma("unroll") for (int ks = 0; ks < 2; ++ks)                     \
            acc[(IH) * 4 + ii][(JH) * 2 + jj] =                              \
                __builtin_amdgcn_mfma_f32_16x16x32_bf16(                     \
                    af[ii][ks], bfr[(JH) * 2 + jj][ks],                      \
                    acc[(IH) * 4 + ii][(JH) * 2 + jj], 0, 0, 0);             \
        __builtin_amdgcn_s_setprio(0);                                       \
    } while (0)

    floatx4 acc[8][4];
#pragma unroll
    for (int i = 0; i < 8; ++i)
#pragma unroll
        for (int j = 0; j < 4; ++j)
            acc[i][j] = (floatx4){0.f, 0.f, 0.f, 0.f};

    short8 af[4][2];
    short8 bfr[4][2];

    const int NT = K_DIM / 64;   // 16

    STAGE_A(0, 0, 0); STAGE_A(1, 0, 0); STAGE_B(0, 0, 0); STAGE_B(1, 0, 0);
    STAGE_A(0, 1, 1); STAGE_B(1, 1, 1); STAGE_B(0, 1, 1);
    asm volatile("s_waitcnt vmcnt(6)" ::: "memory");
    FENCE; BAR;

    for (int g = 0; g < NT; ++g) {
        const int pb = g & 1;
        const int po = pb ^ 1;

        LD_A8(0); LD_B8(0);
        if (g + 1 < NT) STAGE_A(1, g + 1, po);
        FENCE; BAR; LGKM0; SCHED0;
        MM8(0, 0);
        SCHED0; FENCE; BAR;

        LD_B8(1);
        if (g + 2 < NT) STAGE_A(0, g + 2, pb);
        FENCE; BAR; LGKM0; SCHED0;
        MM8(0, 1);
        SCHED0; FENCE; BAR;

        LD_A8(1);
        if (g + 2 < NT) STAGE_B(1, g + 2, pb);
        FENCE; BAR; LGKM0; SCHED0;
        MM8(1, 0);
        SCHED0; FENCE; BAR;

        if (g + 2 < NT) STAGE_B(0, g + 2, pb);
        if (g < NT - 2) {
            asm volatile("s_waitcnt vmcnt(6)" ::: "memory");
        } else if (g == NT - 2) {
            asm volatile("s_waitcnt vmcnt(0)" ::: "memory");
        }
        FENCE; BAR; LGKM0; SCHED0;
        MM8(1, 1);
        SCHED0; FENCE; BAR;
    }
    asm volatile("s_waitcnt vmcnt(0)" ::: "memory");

    float bb[4];
#pragma unroll
    for (int j = 0; j < 4; ++j) bb[j] = bias[bn0 + wn * 64 + j * 16 + l15];
#pragma unroll
    for (int i = 0; i < 8; ++i) {
        int rowb = bm0 + wm * 128 + i * 16 + quad * 4;
#pragma unroll
        for (int r = 0; r < 4; ++r) {
            size_t rb = (size_t)(rowb + r) * N_DIM + bn0 + wn * 64 + l15;
#pragma unroll
            for (int j = 0; j < 4; ++j)
                outBf[rb + j * 16] = f2bf(acc[i][j][r] + bb[j]);
        }
    }
#undef STAGE_A
#undef STAGE_B
#undef LD_A8
#undef LD_B8
#undef MM8
#undef FENCE
#undef BAR
#undef LGKM0
#undef SCHED0
}

// ---------------------------------------------------------------------------
// Reduce-then-scan over T, 2-wide over o (dword = 2 bf16), unroll 32.
// ---------------------------------------------------------------------------
__global__ __launch_bounds__(256) void scan_carry2(
    const uint32* __restrict__ cur32,         // [M, N/2] (bf16 pairs)
    const float* __restrict__ decay,
    float* __restrict__ carry) {              // [B, NCHUNK, N]
    int tid   = blockIdx.x * 256 + threadIdx.x;   // 0 .. 131071
    int o2    = tid & 511;
    int chunk = (tid >> 9) & (NCHUNK - 1);
    int b     = tid >> 12;
    int o     = o2 * 2;
    size_t base = ((size_t)b * T_DIM + (size_t)chunk * CHUNK_T) * (N_DIM / 2) + o2;
    float2 a2 = *(const float2*)&decay[o];
    float a0 = a2.x, a1 = a2.y;
    float c0 = 1.f - a0, c1 = 1.f - a1;
    float u0 = 0.f, u1 = 0.f;
    for (int t0 = 0; t0 < CHUNK_T; t0 += 32) {
        uint32 x[32];
#pragma unroll
        for (int k = 0; k < 32; ++k)
            x[k] = cur32[base + (size_t)(t0 + k) * (N_DIM / 2)];
#pragma unroll
        for (int k = 0; k < 32; ++k) {
            float lo = __uint_as_float(x[k] << 16);
            float hi = __uint_as_float(x[k] & 0xffff0000u);
            u0 = a0 * u0 + c0 * lo;
            u1 = a1 * u1 + c1 * hi;
        }
    }
    float2* cw = (float2*)&carry[((size_t)b * NCHUNK + chunk) * N_DIM + o];
    *cw = (float2){u0, u1};
}

__global__ __launch_bounds__(256) void scan_apply2(
    const uint32* __restrict__ cur32,         // [M, N/2] (bf16 pairs)
    const float* __restrict__ decay,
    const float* __restrict__ carry,          // [B, NCHUNK, N]
    float* __restrict__ out) {                // [M, N] fp32
    int tid   = blockIdx.x * 256 + threadIdx.x;
    int o2    = tid & 511;
    int chunk = (tid >> 9) & (NCHUNK - 1);
    int b     = tid >> 12;
    int o     = o2 * 2;
    size_t base = ((size_t)b * T_DIM + (size_t)chunk * CHUNK_T) * (N_DIM / 2) + o2;
    float2 a2 = *(const float2*)&decay[o];
    float a0 = a2.x, a1 = a2.y;
    float c0 = 1.f - a0, c1 = 1.f - a1;

    float A0 = a0, A1 = a1;
#pragma unroll
    for (int i = 0; i < 7; ++i) { A0 *= A0; A1 *= A1; }   // a^128

    float u0 = 0.f, u1 = 0.f;
    const float* cb = carry + (size_t)b * NCHUNK * N_DIM + o;
    for (int i = 0; i < chunk; ++i) {         // wave-uniform trip count
        float2 cv = *(const float2*)&cb[(size_t)i * N_DIM];
        u0 = cv.x + A0 * u0;
        u1 = cv.y + A1 * u1;
    }

    float2* out2 = (float2*)out;
    size_t obase = ((size_t)b * T_DIM + (size_t)chunk * CHUNK_T) * (N_DIM / 2) + o2;
    for (int t0 = 0; t0 < CHUNK_T; t0 += 32) {
        uint32 x[32];
#pragma unroll
        for (int k = 0; k < 32; ++k)
            x[k] = cur32[base + (size_t)(t0 + k) * (N_DIM / 2)];
#pragma unroll
        for (int k = 0; k < 32; ++k) {
            float lo = __uint_as_float(x[k] << 16);
            float hi = __uint_as_float(x[k] & 0xffff0000u);
            u0 = a0 * u0 + c0 * lo;
            u1 = a1 * u1 + c1 * hi;
            out2[obase + (size_t)(t0 + k) * (N_DIM / 2)] = (float2){u0, u1};
        }
    }
}

// ---------------------------------------------------------------------------
// Fallbacks (only used if workspace too small for the bf16 path)
// ---------------------------------------------------------------------------
__global__ void scan_f32_inplace(float* __restrict__ buf,
                                 const float* __restrict__ decay) {
    int tid = blockIdx.x * 64 + threadIdx.x;
    int o = tid & (N_DIM - 1);
    size_t base = ((size_t)(tid >> 10) << 20) + o;
    float a = decay[o];
    float c = 1.f - a;
    float u = 0.f;
    for (int t0 = 0; t0 < 1024; t0 += 16) {
        float x[16];
#pragma unroll
        for (int k = 0; k < 16; ++k)
            x[k] = buf[base + (size_t)(t0 + k) * N_DIM];
#pragma unroll
        for (int k = 0; k < 16; ++k) {
            u = a * u + c * x[k];
            buf[base + (size_t)(t0 + k) * N_DIM] = u;
        }
    }
}

__global__ __launch_bounds__(256) void gemm_mfma(
    const unsigned short* __restrict__ A,
    const unsigned short* __restrict__ Bw,
    const float* __restrict__ bias,
    unsigned short* outBf,
    float* outF) {
    __shared__ unsigned short As[128 * 64];
    __shared__ unsigned short Bs[128 * 64];

    const int tid  = threadIdx.x;
    const int lane = tid & 63;
    const int wid  = tid >> 6;
    const int l15  = lane & 15;
    const int quad = lane >> 4;
    const int wm   = wid >> 1;
    const int wn   = wid & 1;

    const int L    = blockIdx.y * gridDim.x + blockIdx.x;
    const int xcd  = L & 7;
    const int s    = L >> 3;
    const int bn0  = (s & 7) * 128;
    const int bm0  = (xcd * 32 + (s >> 3)) * 128;

    floatx4 acc[4][4];
#pragma unroll
    for (int i = 0; i < 4; ++i)
#pragma unroll
        for (int j = 0; j < 4; ++j)
            acc[i][j] = (floatx4){0.f, 0.f, 0.f, 0.f};

    for (int kt = 0; kt < K_DIM / 64; ++kt) {
        const int k0 = kt * 64;
#pragma unroll
        for (int q = 0; q < 4; ++q) {
            int slot = q * 256 + tid;
            int row  = slot >> 3;
            int chq  = slot & 7;
            int scq  = chq ^ (row & 7);
            async_load16(A + (size_t)(bm0 + row) * K_DIM + k0 + scq * 8,
                         &As[(q * 256 + wid * 64) * 8]);
        }
#pragma unroll
        for (int q = 0; q < 4; ++q) {
            int slot = q * 256 + tid;
            int row  = slot >> 3;
            int chq  = slot & 7;
            int scq  = chq ^ (row & 7);
            async_load16(Bw + (size_t)(bn0 + row) * K_DIM + k0 + scq * 8,
                         &Bs[(q * 256 + wid * 64) * 8]);
        }
        __syncthreads();

#pragma unroll
        for (int ks = 0; ks < 2; ++ks) {
            short8 af[4], bfr[4];
#pragma unroll
            for (int i = 0; i < 4; ++i) {
                int r = wm * 64 + i * 16 + l15;
                int c = ks * 4 + quad;
                af[i] = *(const short8*)&As[r * 64 + ((c ^ (r & 7)) * 8)];
            }
#pragma unroll
            for (int j = 0; j < 4; ++j) {
                int r = wn * 64 + j * 16 + l15;
                int c = ks * 4 + quad;
                bfr[j] = *(const short8*)&Bs[r * 64 + ((c ^ (r & 7)) * 8)];
            }
#pragma unroll
            for (int i = 0; i < 4; ++i)
#pragma unroll
                for (int j = 0; j < 4; ++j)
                    acc[i][j] = __builtin_amdgcn_mfma_f32_16x16x32_bf16(
                        af[i], bfr[j], acc[i][j], 0, 0, 0);
        }
        __syncthreads();
    }

#pragma unroll
    for (int j = 0; j < 4; ++j) {
        int col = bn0 + wn * 64 + j * 16 + l15;
        float bb = bias[col];
#pragma unroll
        for (int i = 0; i < 4; ++i) {
            int rowb = bm0 + wm * 64 + i * 16 + quad * 4;
#pragma unroll
            for (int r = 0; r < 4; ++r) {
                float v = acc[i][j][r] + bb;
                size_t idx = (size_t)(rowb + r) * N_DIM + col;
                if (outBf) outBf[idx] = f2bf(v);
                else       outF[idx]  = v;
            }
        }
    }
}

__global__ void gemm_naive(const float* __restrict__ X, const float* __restrict__ W,
                           const float* __restrict__ bias, float* __restrict__ out) {
    __shared__ float As[16][17], Bs[16][17];
    int tx = threadIdx.x, ty = threadIdx.y;
    int m0 = blockIdx.y * 16, n0 = blockIdx.x * 16;
    float acc = 0.f;
    for (int k0 = 0; k0 < K_DIM; k0 += 16) {
        As[ty][tx] = X[(size_t)(m0 + ty) * K_DIM + k0 + tx];
        Bs[ty][tx] = W[(size_t)(n0 + ty) * K_DIM + k0 + tx];
        __syncthreads();
#pragma unroll
        for (int kk = 0; kk < 16; ++kk) acc += As[ty][kk] * Bs[tx][kk];
        __syncthreads();
    }
    out[(size_t)(m0 + ty) * N_DIM + n0 + tx] = acc + bias[n0 + tx];
}

// ---------------------------------------------------------------------------
extern "C" void kernel_launch(void* const* d_in, const int* in_sizes, int n_in,
                              void* d_out, int out_size, void* d_ws, size_t ws_size,
                              hipStream_t stream) {
    const float* X     = (const float*)d_in[0];  // [B,T,IN]  = [M,K]
    const float* Wt    = (const float*)d_in[1];  // [OUT,IN]  = [N,K]
    const float* bias  = (const float*)d_in[2];  // [OUT]
    const float* decay = (const float*)d_in[3];  // [OUT]
    float* out = (float*)d_out;                  // [B,T,OUT] = [M,N]

    // One-time LDS opt-ins (host-side, capture-safe).
    static bool lds144_ok = [] {
        return hipFuncSetAttribute(reinterpret_cast<const void*>(gemm_f32a),
                                   hipFuncAttributeMaxDynamicSharedMemorySize,
                                   147456) == hipSuccess;
    }();
    static bool lds128_ok = [] {
        return hipFuncSetAttribute(reinterpret_cast<const void*>(gemm_8phase),
                                   hipFuncAttributeMaxDynamicSharedMemorySize,
                                   131072) == hipSuccess;
    }();

    const size_t A_bytes  = (size_t)M_DIM * K_DIM * 2;            // 64 MB
    const size_t W_bytes  = (size_t)N_DIM * K_DIM * 2;            // 2 MB
    const size_t C_bytes  = (size_t)M_DIM * N_DIM * 2;            // 64 MB
    const size_t cr_bytes = (size_t)B_DIM * NCHUNK * N_DIM * 4;   // 1 MB
    const size_t need_new  = W_bytes + C_bytes + cr_bytes;        // ~67 MB
    const size_t need_mid  = A_bytes + W_bytes;
    const size_t need_full = A_bytes + W_bytes + C_bytes + cr_bytes;
    const int scan_threads = B_DIM * NCHUNK * N_DIM / 2;          // 131072

    if (lds144_ok && ws_size >= need_new) {
        unsigned short* Wbf = (unsigned short*)d_ws;
        unsigned short* Cbf = (unsigned short*)((char*)d_ws + W_bytes);
        float* carry = (float*)((char*)d_ws + W_bytes + C_bytes);
        cast_f32_bf16_x8<<<(N_DIM * K_DIM / 8 + 255) / 256, 256, 0, stream>>>(Wt, Wbf, N_DIM * K_DIM / 8);
        gemm_f32a<<<dim3(4, 128), 512, 147456, stream>>>(X, Wbf, bias, Cbf);
        scan_carry2<<<scan_threads / 256, 256, 0, stream>>>((const uint32*)Cbf, decay, carry);
        scan_apply2<<<scan_threads / 256, 256, 0, stream>>>((const uint32*)Cbf, decay, carry, out);
    } else if (lds128_ok && ws_size >= need_full) {
        unsigned short* Abf = (unsigned short*)d_ws;
        unsigned short* Wbf = (unsigned short*)((char*)d_ws + A_bytes);
        unsigned short* Cbf = (unsigned short*)((char*)d_ws + A_bytes + W_bytes);
        float* carry = (float*)((char*)d_ws + A_bytes + W_bytes + C_bytes);
        cast_f32_bf16_x8<<<(M_DIM * K_DIM / 8 + 255) / 256, 256, 0, stream>>>(X, Abf, M_DIM * K_DIM / 8);
        cast_f32_bf16_x8<<<(N_DIM * K_DIM / 8 + 255) / 256, 256, 0, stream>>>(Wt, Wbf, N_DIM * K_DIM / 8);
        gemm_8phase<<<dim3(4, 128), 512, 131072, stream>>>(Abf, Wbf, bias, Cbf);
        scan_carry2<<<scan_threads / 256, 256, 0, stream>>>((const uint32*)Cbf, decay, carry);
        scan_apply2<<<scan_threads / 256, 256, 0, stream>>>((const uint32*)Cbf, decay, carry, out);
    } else if (ws_size >= need_mid) {
        unsigned short* Abf = (unsigned short*)d_ws;
        unsigned short* Wbf = (unsigned short*)((char*)d_ws + A_bytes);
        cast_f32_bf16_x8<<<(M_DIM * K_DIM / 8 + 255) / 256, 256, 0, stream>>>(X, Abf, M_DIM * K_DIM / 8);
        cast_f32_bf16_x8<<<(N_DIM * K_DIM / 8 + 255) / 256, 256, 0, stream>>>(Wt, Wbf, N_DIM * K_DIM / 8);
        gemm_mfma<<<dim3(N_DIM / 128, M_DIM / 128), 256, 0, stream>>>(Abf, Wbf, bias, nullptr, out);
        scan_f32_inplace<<<512, 64, 0, stream>>>(out, decay);
    } else {
        gemm_naive<<<dim3(N_DIM / 16, M_DIM / 16), dim3(16, 16), 0, stream>>>(X, Wt, bias, out);
        scan_f32_inplace<<<512, 64, 0, stream>>>(out, decay);
    }
}

// Round 5
// 153.832 us; speedup vs baseline: 1.1361x; 1.1361x over previous
//
#include <hip/hip_runtime.h>

// Problem constants: B=32, T=1024, IN=1024, OUT=1024
// M = B*T = 32768, K = IN = 1024, N = OUT = 1024
#define M_DIM 32768
#define N_DIM 1024
#define K_DIM 1024
#define T_DIM 1024
#define B_DIM 32
#define NCHUNK 8
#define CHUNK_T 128   // T_DIM / NCHUNK

typedef unsigned int uint32;
typedef __attribute__((ext_vector_type(8))) short short8;       // 8 bf16 (MFMA A/B frag)
typedef __attribute__((ext_vector_type(8))) unsigned short ushort8v;
typedef __attribute__((ext_vector_type(4))) float floatx4;      // MFMA C/D frag + asm loads

__device__ __forceinline__ unsigned short f2bf(float f) {
    uint32 u = __float_as_uint(f);
    uint32 r = u + 0x7fffu + ((u >> 16) & 1u);
    return (unsigned short)(r >> 16);
}

__device__ __forceinline__ void async_load16(const void* g, void* s) {
    __builtin_amdgcn_global_load_lds(
        (const __attribute__((address_space(1))) void*)g,
        (__attribute__((address_space(3))) void*)s,
        16, 0, 0);
}

// 8 f32 -> short8 of bf16 via v_cvt_pk_bf16_f32 (RNE, same as f2bf).
// NOTE: operands are ext_vector floatx4 elements (scalars) — never pass HIP
// struct float4 into asm "v" operands (R4 crash: aggregate in "v" clobbers
// neighboring VGPRs).
__device__ __forceinline__ short8 pk8(floatx4 a, floatx4 b) {
    union { short8 s; uint32 d[4]; } u;
    asm("v_cvt_pk_bf16_f32 %0, %1, %2" : "=v"(u.d[0]) : "v"(a[0]), "v"(a[1]));
    asm("v_cvt_pk_bf16_f32 %0, %1, %2" : "=v"(u.d[1]) : "v"(a[2]), "v"(a[3]));
    asm("v_cvt_pk_bf16_f32 %0, %1, %2" : "=v"(u.d[2]) : "v"(b[0]), "v"(b[1]));
    asm("v_cvt_pk_bf16_f32 %0, %1, %2" : "=v"(u.d[3]) : "v"(b[2]), "v"(b[3]));
    return u.s;
}

// ---- shared schedule macros ------------------------------------------------
#define FENCE  asm volatile("" ::: "memory")
#define BAR    __builtin_amdgcn_s_barrier()
#define LGKM0  asm volatile("s_waitcnt lgkmcnt(0)" ::: "memory")
#define SCHED0 __builtin_amdgcn_sched_barrier(0)
#define VMW(N) asm volatile("s_waitcnt vmcnt(" #N ")" ::: "memory")

// B half-tile JH of K-tile T -> buf PB (R2 pattern, measured conflict-free).
#define STAGE_B(JH, T, PB) do {                                              \
        size_t kof_ = (size_t)(T) * 64 + sc8;                                \
        _Pragma("unroll") for (int q_ = 0; q_ < 2; ++q_) {                   \
            int br_ = (q_ * 2 + (tid >> 8)) * 64 + (JH) * 32 + (t3 & 31);    \
            int dr_ = (q_ * 2 + (wid >> 2)) * 64 + (JH) * 32 + (wid & 3) * 8;\
            async_load16(Bw + (size_t)(bn0 + br_) * K_DIM + kof_,            \
                         smem + (PB) * 32768 + 16384 + dr_ * 64);            \
        } } while (0)

// Fragment loads (R2 pattern, measured conflict-free).
#define LD_A8(IH) do {                                                       \
        const unsigned short* As_ = smem + pb * 32768;                       \
        _Pragma("unroll") for (int ii = 0; ii < 4; ++ii) {                   \
            int r_ = wm * 128 + (IH) * 64 + ii * 16 + l15;                   \
            _Pragma("unroll") for (int ks = 0; ks < 2; ++ks) {               \
                int c_ = ks * 4 + quad;                                      \
                af[ii][ks] = *(const short8*)&As_[r_ * 64 +                  \
                                                 ((c_ ^ (l15 & 7)) * 8)];    \
            } } } while (0)
#define LD_B8(JH) do {                                                       \
        const unsigned short* Bs_ = smem + pb * 32768 + 16384;               \
        _Pragma("unroll") for (int jj = 0; jj < 2; ++jj) {                   \
            int r_ = wn * 64 + ((JH) * 2 + jj) * 16 + l15;                   \
            _Pragma("unroll") for (int ks = 0; ks < 2; ++ks) {               \
                int c_ = ks * 4 + quad;                                      \
                bfr[(JH) * 2 + jj][ks] = *(const short8*)&Bs_[r_ * 64 +      \
                                                 ((c_ ^ (l15 & 7)) * 8)];    \
            } } } while (0)
#define MM8(IH, JH) do {                                                     \
        __builtin_amdgcn_s_setprio(1);                                       \
        _Pragma("unroll") for (int ii = 0; ii < 4; ++ii)                     \
        _Pragma("unroll") for (int jj = 0; jj < 2; ++jj)                     \
        _Pragma("unroll") for (int ks = 0; ks < 2; ++ks)                     \
            acc[(IH) * 4 + ii][(JH) * 2 + jj] =                              \
                __builtin_amdgcn_mfma_f32_16x16x32_bf16(                     \
                    af[ii][ks], bfr[(JH) * 2 + jj][ks],                      \
                    acc[(IH) * 4 + ii][(JH) * 2 + jj], 0, 0, 0);             \
        __builtin_amdgcn_s_setprio(0);                                       \
    } while (0)

// A reg-staging (cast-fused). Slot P holds f32 pair for row quarter P.
// ext_vector outputs + early-clobber (R4 fix).
#define AISSUE(P, T) do {                                                    \
        const float* p_ = abase[P] + (T) * 64;                               \
        asm volatile("global_load_dwordx4 %0, %1, off"                       \
                     : "=&v"(ar[2 * (P)]) : "v"(p_));                        \
        asm volatile("global_load_dwordx4 %0, %1, off offset:16"             \
                     : "=&v"(ar[2 * (P) + 1]) : "v"(p_));                    \
    } while (0)
// Convert + swizzled ds_write into buf PBDST (content layout == R2's DMA:
// LDS chunk position p of row r holds global chunk p ^ (r&7)).
#define AWRITE(P, PBDST) do {                                                \
        int row_ = (P) * 64 + (tid >> 3);                                    \
        int cs_  = (tid & 7) ^ (row_ & 7);                                   \
        *(short8*)&smem[(PBDST) * 32768 + row_ * 64 + cs_ * 8] =             \
            pk8(ar[2 * (P)], ar[2 * (P) + 1]);                               \
    } while (0)

// ---------------------------------------------------------------------------
// fp32 -> bf16 cast, 8 elems/thread (16B store). W (2 MB) on main path;
// A-cast only in fallback.
// ---------------------------------------------------------------------------
__global__ void cast_f32_bf16_x8(const float* __restrict__ src,
                                 unsigned short* __restrict__ dst, int n8) {
    int i = blockIdx.x * blockDim.x + threadIdx.x;
    if (i < n8) {
        const float4* s4 = (const float4*)src;
        float4 v0 = s4[(size_t)i * 2];
        float4 v1 = s4[(size_t)i * 2 + 1];
        ushort8v o;
        o[0] = f2bf(v0.x); o[1] = f2bf(v0.y); o[2] = f2bf(v0.z); o[3] = f2bf(v0.w);
        o[4] = f2bf(v1.x); o[5] = f2bf(v1.y); o[6] = f2bf(v1.z); o[7] = f2bf(v1.w);
        ((ushort8v*)dst)[i] = o;
    }
}

// ---------------------------------------------------------------------------
// MAIN GEMM: R2's verified 8-phase 256x256/BK=64 structure, A-cast fused via
// reg-staging: per phase, 2 asm global_load_dwordx4 of X-f32 ->
// v_cvt_pk_bf16_f32 -> 1 swizzled ds_write_b128 into the SAME [256][64] bf16
// LDS layout R2's conflict-free ds_reads consume. B via global_load_lds as R2.
//
// vmcnt ledger (simulated tile-by-tile, steady state):
//   entering p0(g): Q = [A0(g+1)?drained, B0(g+1), A1, A2, B1, A3, A0(g+2)...]
//   vm(8) at every phase; outstanding oscillates 8..12, never < 8.
//   Each AWRITE(P)'s operand (A-quarter P of tile g+1, issued at pP(g-1)) is
//   provably drained by the vm(8) at or before pP(g). B0(g+2)/B1(g+2) DMA
//   drain at p0(g+1)/p2(g+1), both >= 1 barrier before their tile-(g+2) reads.
//   Tail (tile 14): 8/5/3/0. Tile 15: compute only (vmcnt already 0).
// AWRITE targets buf pb^1 (tile g-1's buffer, all reads of which completed
// before p3(g-1)'s end-barrier). STAGE_B writes regions of buf pb whose
// reads completed earlier in this tile (+ >=1 barrier).
// ---------------------------------------------------------------------------
__global__ __launch_bounds__(512, 2) void gemm_fused(
    const float* __restrict__ X32,          // [M, K] fp32
    const unsigned short* __restrict__ Bw,  // [N, K] bf16
    const float* __restrict__ bias,         // [N]
    unsigned short* __restrict__ outBf) {   // [M, N] bf16
    extern __shared__ __align__(16) unsigned short smem[];  // 131072 B

    const int tid  = threadIdx.x;
    const int lane = tid & 63;
    const int wid  = tid >> 6;      // 0..7
    const int l15  = lane & 15;
    const int quad = lane >> 4;
    const int wm   = wid >> 2;      // 0..1
    const int wn   = wid & 3;       // 0..3

    // XCD-aware remap: 512 blocks; xcd owns 16 M-panels, 4 N-tiles each.
    const int L   = blockIdx.y * gridDim.x + blockIdx.x;   // 0..511
    const int xcd = L & 7;
    const int s   = L >> 3;
    const int bn0 = (s & 3) * 256;
    const int bm0 = (xcd * 16 + (s >> 2)) * 256;

    const int t3  = tid >> 3;                               // 0..63
    const int sc8 = ((tid & 7) ^ (t3 & 7)) * 8;             // B-staging swizzle

    // A-source base per row-quarter (thread-fixed; +T*64 floats per K-tile).
    const float* abase[4];
#pragma unroll
    for (int p = 0; p < 4; ++p)
        abase[p] = X32 + (size_t)(bm0 + p * 64 + (tid >> 3)) * K_DIM + (tid & 7) * 8;

    floatx4 acc[8][4];
#pragma unroll
    for (int i = 0; i < 8; ++i)
#pragma unroll
        for (int j = 0; j < 4; ++j)
            acc[i][j] = (floatx4){0.f, 0.f, 0.f, 0.f};

    short8 af[4][2];
    short8 bfr[4][2];
    floatx4 ar[8];                   // in-flight A f32 (literal indices only)

    // Prologue: tile 0 (A loads + B DMA), early-drain A, write buf0, then
    // tile 1 issued in steady order, drain tile 0's B.
    AISSUE(0, 0); AISSUE(1, 0); AISSUE(2, 0); AISSUE(3, 0);
    STAGE_B(0, 0, 0); STAGE_B(1, 0, 0);
    VMW(2); SCHED0;
    AWRITE(0, 0); AWRITE(1, 0); AWRITE(2, 0); AWRITE(3, 0);
    AISSUE(0, 1); STAGE_B(0, 1, 1); AISSUE(1, 1); AISSUE(2, 1);
    STAGE_B(1, 1, 1); AISSUE(3, 1);
    VMW(10); LGKM0; FENCE; BAR;

    // Main loop: tiles 0..13 (issues gens 2..15, all valid).
#define TILE_MAIN(G) do {                                                    \
        const int pb = (G) & 1;                                              \
        LD_A8(0); LD_B8(0);                                                  \
        VMW(8); SCHED0; AWRITE(0, pb ^ 1); AISSUE(0, (G) + 2);               \
        LGKM0; BAR; SCHED0; MM8(0, 0); BAR;                                  \
        LD_B8(1); STAGE_B(0, (G) + 2, pb);                                   \
        VMW(8); SCHED0; AWRITE(1, pb ^ 1); AISSUE(1, (G) + 2);               \
        LGKM0; BAR; SCHED0; MM8(0, 1); BAR;                                  \
        LD_A8(1);                                                            \
        VMW(8); SCHED0; AWRITE(2, pb ^ 1); AISSUE(2, (G) + 2);               \
        LGKM0; BAR; SCHED0; MM8(1, 0); BAR;                                  \
        STAGE_B(1, (G) + 2, pb);                                             \
        VMW(8); SCHED0; AWRITE(3, pb ^ 1); AISSUE(3, (G) + 2);               \
        LGKM0; BAR; SCHED0; MM8(1, 1); BAR;                                  \
    } while (0)

    for (int g = 0; g < 14; ++g) TILE_MAIN(g);

    // Tile 14 (pb=0): no issues; tail drains 8/5/3/0; writes tile-15 A -> buf1.
    {
        const int pb = 0;
        LD_A8(0); LD_B8(0);
        VMW(8); SCHED0; AWRITE(0, 1);
        LGKM0; BAR; SCHED0; MM8(0, 0); BAR;
        LD_B8(1);
        VMW(5); SCHED0; AWRITE(1, 1);
        LGKM0; BAR; SCHED0; MM8(0, 1); BAR;
        LD_A8(1);
        VMW(3); SCHED0; AWRITE(2, 1);
        LGKM0; BAR; SCHED0; MM8(1, 0); BAR;
        VMW(0); SCHED0; AWRITE(3, 1);
        LGKM0; BAR; SCHED0; MM8(1, 1); BAR;
    }
    // Tile 15 (pb=1): compute only (vmcnt == 0).
    {
        const int pb = 1;
        LD_A8(0); LD_B8(0); LGKM0; BAR; SCHED0; MM8(0, 0); BAR;
        LD_B8(1);           LGKM0; BAR; SCHED0; MM8(0, 1); BAR;
        LD_A8(1);           LGKM0; BAR; SCHED0; MM8(1, 0); BAR;
                            LGKM0; BAR; SCHED0; MM8(1, 1); BAR;
    }
#undef TILE_MAIN

    // Epilogue: C/D layout col = lane&15, row = quad*4 + reg; j innermost so
    // each 128B C-line's 4x32B pieces issue back-to-back (no write amp).
    float bb[4];
#pragma unroll
    for (int j = 0; j < 4; ++j) bb[j] = bias[bn0 + wn * 64 + j * 16 + l15];
#pragma unroll
    for (int i = 0; i < 8; ++i) {
        int rowb = bm0 + wm * 128 + i * 16 + quad * 4;
#pragma unroll
        for (int r = 0; r < 4; ++r) {
            size_t rb = (size_t)(rowb + r) * N_DIM + bn0 + wn * 64 + l15;
#pragma unroll
            for (int j = 0; j < 4; ++j)
                outBf[rb + j * 16] = f2bf(acc[i][j][r] + bb[j]);
        }
    }
}

// ---------------------------------------------------------------------------
// R2 8-phase bf16 GEMM — fallback (needs pre-cast A).
// ---------------------------------------------------------------------------
__global__ __launch_bounds__(512, 2) void gemm_8phase(
    const unsigned short* __restrict__ A,   // [M, K] bf16
    const unsigned short* __restrict__ Bw,  // [N, K] bf16
    const float* __restrict__ bias,         // [N]
    unsigned short* __restrict__ outBf) {   // [M, N] bf16
    extern __shared__ __align__(16) unsigned short smem[];  // 131072 B

    const int tid  = threadIdx.x;
    const int lane = tid & 63;
    const int wid  = tid >> 6;
    const int l15  = lane & 15;
    const int quad = lane >> 4;
    const int wm   = wid >> 2;
    const int wn   = wid & 3;

    const int L   = blockIdx.y * gridDim.x + blockIdx.x;
    const int xcd = L & 7;
    const int s   = L >> 3;
    const int bn0 = (s & 3) * 256;
    const int bm0 = (xcd * 16 + (s >> 2)) * 256;

    const int t3  = tid >> 3;
    const int sc8 = ((tid & 7) ^ (t3 & 7)) * 8;

#define STAGE_A(IH, T, PB) do {                                              \
        size_t kof_ = (size_t)(T) * 64 + sc8;                                \
        _Pragma("unroll") for (int q_ = 0; q_ < 2; ++q_) {                   \
            int ar_ = q_ * 128 + (IH) * 64 + t3;                             \
            int dr_ = q_ * 128 + (IH) * 64 + wid * 8;                        \
            async_load16(A + (size_t)(bm0 + ar_) * K_DIM + kof_,             \
                         smem + (PB) * 32768 + dr_ * 64);                    \
        } } while (0)

    floatx4 acc[8][4];
#pragma unroll
    for (int i = 0; i < 8; ++i)
#pragma unroll
        for (int j = 0; j < 4; ++j)
            acc[i][j] = (floatx4){0.f, 0.f, 0.f, 0.f};

    short8 af[4][2];
    short8 bfr[4][2];

    const int NT = K_DIM / 64;   // 16

    STAGE_A(0, 0, 0); STAGE_A(1, 0, 0); STAGE_B(0, 0, 0); STAGE_B(1, 0, 0);
    STAGE_A(0, 1, 1); STAGE_B(1, 1, 1); STAGE_B(0, 1, 1);
    asm volatile("s_waitcnt vmcnt(6)" ::: "memory");
    FENCE; BAR;

    for (int g = 0; g < NT; ++g) {
        const int pb = g & 1;
        const int po = pb ^ 1;

        LD_A8(0); LD_B8(0);
        if (g + 1 < NT) STAGE_A(1, g + 1, po);
        FENCE; BAR; LGKM0; SCHED0;
        MM8(0, 0);
        SCHED0; FENCE; BAR;

        LD_B8(1);
        if (g + 2 < NT) STAGE_A(0, g + 2, pb);
        FENCE; BAR; LGKM0; SCHED0;
        MM8(0, 1);
        SCHED0; FENCE; BAR;

        LD_A8(1);
        if (g + 2 < NT) STAGE_B(1, g + 2, pb);
        FENCE; BAR; LGKM0; SCHED0;
        MM8(1, 0);
        SCHED0; FENCE; BAR;

        if (g + 2 < NT) STAGE_B(0, g + 2, pb);
        if (g < NT - 2) {
            asm volatile("s_waitcnt vmcnt(6)" ::: "memory");
        } else if (g == NT - 2) {
            asm volatile("s_waitcnt vmcnt(0)" ::: "memory");
        }
        FENCE; BAR; LGKM0; SCHED0;
        MM8(1, 1);
        SCHED0; FENCE; BAR;
    }
    asm volatile("s_waitcnt vmcnt(0)" ::: "memory");

    float bb[4];
#pragma unroll
    for (int j = 0; j < 4; ++j) bb[j] = bias[bn0 + wn * 64 + j * 16 + l15];
#pragma unroll
    for (int i = 0; i < 8; ++i) {
        int rowb = bm0 + wm * 128 + i * 16 + quad * 4;
#pragma unroll
        for (int r = 0; r < 4; ++r) {
            size_t rb = (size_t)(rowb + r) * N_DIM + bn0 + wn * 64 + l15;
#pragma unroll
            for (int j = 0; j < 4; ++j)
                outBf[rb + j * 16] = f2bf(acc[i][j][r] + bb[j]);
        }
    }
#undef STAGE_A
}

// ---------------------------------------------------------------------------
// Reduce-then-scan over T, 2-wide over o (dword = 2 bf16), unroll 32.
// ---------------------------------------------------------------------------
__global__ __launch_bounds__(256) void scan_carry2(
    const uint32* __restrict__ cur32,         // [M, N/2] (bf16 pairs)
    const float* __restrict__ decay,
    float* __restrict__ carry) {              // [B, NCHUNK, N]
    int tid   = blockIdx.x * 256 + threadIdx.x;   // 0 .. 131071
    int o2    = tid & 511;
    int chunk = (tid >> 9) & (NCHUNK - 1);
    int b     = tid >> 12;
    int o     = o2 * 2;
    size_t base = ((size_t)b * T_DIM + (size_t)chunk * CHUNK_T) * (N_DIM / 2) + o2;
    float2 a2 = *(const float2*)&decay[o];
    float a0 = a2.x, a1 = a2.y;
    float c0 = 1.f - a0, c1 = 1.f - a1;
    float u0 = 0.f, u1 = 0.f;
    for (int t0 = 0; t0 < CHUNK_T; t0 += 32) {
        uint32 x[32];
#pragma unroll
        for (int k = 0; k < 32; ++k)
            x[k] = cur32[base + (size_t)(t0 + k) * (N_DIM / 2)];
#pragma unroll
        for (int k = 0; k < 32; ++k) {
            float lo = __uint_as_float(x[k] << 16);
            float hi = __uint_as_float(x[k] & 0xffff0000u);
            u0 = a0 * u0 + c0 * lo;
            u1 = a1 * u1 + c1 * hi;
        }
    }
    float2* cw = (float2*)&carry[((size_t)b * NCHUNK + chunk) * N_DIM + o];
    *cw = (float2){u0, u1};
}

__global__ __launch_bounds__(256) void scan_apply2(
    const uint32* __restrict__ cur32,         // [M, N/2] (bf16 pairs)
    const float* __restrict__ decay,
    const float* __restrict__ carry,          // [B, NCHUNK, N]
    float* __restrict__ out) {                // [M, N] fp32
    int tid   = blockIdx.x * 256 + threadIdx.x;
    int o2    = tid & 511;
    int chunk = (tid >> 9) & (NCHUNK - 1);
    int b     = tid >> 12;
    int o     = o2 * 2;
    size_t base = ((size_t)b * T_DIM + (size_t)chunk * CHUNK_T) * (N_DIM / 2) + o2;
    float2 a2 = *(const float2*)&decay[o];
    float a0 = a2.x, a1 = a2.y;
    float c0 = 1.f - a0, c1 = 1.f - a1;

    float A0 = a0, A1 = a1;
#pragma unroll
    for (int i = 0; i < 7; ++i) { A0 *= A0; A1 *= A1; }   // a^128

    float u0 = 0.f, u1 = 0.f;
    const float* cb = carry + (size_t)b * NCHUNK * N_DIM + o;
    for (int i = 0; i < chunk; ++i) {         // wave-uniform trip count
        float2 cv = *(const float2*)&cb[(size_t)i * N_DIM];
        u0 = cv.x + A0 * u0;
        u1 = cv.y + A1 * u1;
    }

    float2* out2 = (float2*)out;
    size_t obase = ((size_t)b * T_DIM + (size_t)chunk * CHUNK_T) * (N_DIM / 2) + o2;
    for (int t0 = 0; t0 < CHUNK_T; t0 += 32) {
        uint32 x[32];
#pragma unroll
        for (int k = 0; k < 32; ++k)
            x[k] = cur32[base + (size_t)(t0 + k) * (N_DIM / 2)];
#pragma unroll
        for (int k = 0; k < 32; ++k) {
            float lo = __uint_as_float(x[k] << 16);
            float hi = __uint_as_float(x[k] & 0xffff0000u);
            u0 = a0 * u0 + c0 * lo;
            u1 = a1 * u1 + c1 * hi;
            out2[obase + (size_t)(t0 + k) * (N_DIM / 2)] = (float2){u0, u1};
        }
    }
}

// ---------------------------------------------------------------------------
// Fallbacks (only used if workspace too small for the bf16 path)
// ---------------------------------------------------------------------------
__global__ void scan_f32_inplace(float* __restrict__ buf,
                                 const float* __restrict__ decay) {
    int tid = blockIdx.x * 64 + threadIdx.x;
    int o = tid & (N_DIM - 1);
    size_t base = ((size_t)(tid >> 10) << 20) + o;
    float a = decay[o];
    float c = 1.f - a;
    float u = 0.f;
    for (int t0 = 0; t0 < 1024; t0 += 16) {
        float x[16];
#pragma unroll
        for (int k = 0; k < 16; ++k)
            x[k] = buf[base + (size_t)(t0 + k) * N_DIM];
#pragma unroll
        for (int k = 0; k < 16; ++k) {
            u = a * u + c * x[k];
            buf[base + (size_t)(t0 + k) * N_DIM] = u;
        }
    }
}

__global__ __launch_bounds__(256) void gemm_mfma(
    const unsigned short* __restrict__ A,
    const unsigned short* __restrict__ Bw,
    const float* __restrict__ bias,
    unsigned short* outBf,
    float* outF) {
    __shared__ unsigned short As[128 * 64];
    __shared__ unsigned short Bs[128 * 64];

    const int tid  = threadIdx.x;
    const int lane = tid & 63;
    const int wid  = tid >> 6;
    const int l15  = lane & 15;
    const int quad = lane >> 4;
    const int wm   = wid >> 1;
    const int wn   = wid & 1;

    const int L    = blockIdx.y * gridDim.x + blockIdx.x;
    const int xcd  = L & 7;
    const int s    = L >> 3;
    const int bn0  = (s & 7) * 128;
    const int bm0  = (xcd * 32 + (s >> 3)) * 128;

    floatx4 acc[4][4];
#pragma unroll
    for (int i = 0; i < 4; ++i)
#pragma unroll
        for (int j = 0; j < 4; ++j)
            acc[i][j] = (floatx4){0.f, 0.f, 0.f, 0.f};

    for (int kt = 0; kt < K_DIM / 64; ++kt) {
        const int k0 = kt * 64;
#pragma unroll
        for (int q = 0; q < 4; ++q) {
            int slot = q * 256 + tid;
            int row  = slot >> 3;
            int chq  = slot & 7;
            int scq  = chq ^ (row & 7);
            async_load16(A + (size_t)(bm0 + row) * K_DIM + k0 + scq * 8,
                         &As[(q * 256 + wid * 64) * 8]);
        }
#pragma unroll
        for (int q = 0; q < 4; ++q) {
            int slot = q * 256 + tid;
            int row  = slot >> 3;
            int chq  = slot & 7;
            int scq  = chq ^ (row & 7);
            async_load16(Bw + (size_t)(bn0 + row) * K_DIM + k0 + scq * 8,
                         &Bs[(q * 256 + wid * 64) * 8]);
        }
        __syncthreads();

#pragma unroll
        for (int ks = 0; ks < 2; ++ks) {
            short8 af[4], bfr[4];
#pragma unroll
            for (int i = 0; i < 4; ++i) {
                int r = wm * 64 + i * 16 + l15;
                int c = ks * 4 + quad;
                af[i] = *(const short8*)&As[r * 64 + ((c ^ (r & 7)) * 8)];
            }
#pragma unroll
            for (int j = 0; j < 4; ++j) {
                int r = wn * 64 + j * 16 + l15;
                int c = ks * 4 + quad;
                bfr[j] = *(const short8*)&Bs[r * 64 + ((c ^ (r & 7)) * 8)];
            }
#pragma unroll
            for (int i = 0; i < 4; ++i)
#pragma unroll
                for (int j = 0; j < 4; ++j)
                    acc[i][j] = __builtin_amdgcn_mfma_f32_16x16x32_bf16(
                        af[i], bfr[j], acc[i][j], 0, 0, 0);
        }
        __syncthreads();
    }

#pragma unroll
    for (int j = 0; j < 4; ++j) {
        int col = bn0 + wn * 64 + j * 16 + l15;
        float bb = bias[col];
#pragma unroll
        for (int i = 0; i < 4; ++i) {
            int rowb = bm0 + wm * 64 + i * 16 + quad * 4;
#pragma unroll
            for (int r = 0; r < 4; ++r) {
                float v = acc[i][j][r] + bb;
                size_t idx = (size_t)(rowb + r) * N_DIM + col;
                if (outBf) outBf[idx] = f2bf(v);
                else       outF[idx]  = v;
            }
        }
    }
}

__global__ void gemm_naive(const float* __restrict__ X, const float* __restrict__ W,
                           const float* __restrict__ bias, float* __restrict__ out) {
    __shared__ float As[16][17], Bs[16][17];
    int tx = threadIdx.x, ty = threadIdx.y;
    int m0 = blockIdx.y * 16, n0 = blockIdx.x * 16;
    float acc = 0.f;
    for (int k0 = 0; k0 < K_DIM; k0 += 16) {
        As[ty][tx] = X[(size_t)(m0 + ty) * K_DIM + k0 + tx];
        Bs[ty][tx] = W[(size_t)(n0 + ty) * K_DIM + k0 + tx];
        __syncthreads();
#pragma unroll
        for (int kk = 0; kk < 16; ++kk) acc += As[ty][kk] * Bs[tx][kk];
        __syncthreads();
    }
    out[(size_t)(m0 + ty) * N_DIM + n0 + tx] = acc + bias[n0 + tx];
}

// ---------------------------------------------------------------------------
extern "C" void kernel_launch(void* const* d_in, const int* in_sizes, int n_in,
                              void* d_out, int out_size, void* d_ws, size_t ws_size,
                              hipStream_t stream) {
    const float* X     = (const float*)d_in[0];  // [B,T,IN]  = [M,K]
    const float* Wt    = (const float*)d_in[1];  // [OUT,IN]  = [N,K]
    const float* bias  = (const float*)d_in[2];  // [OUT]
    const float* decay = (const float*)d_in[3];  // [OUT]
    float* out = (float*)d_out;                  // [B,T,OUT] = [M,N]

    // One-time LDS opt-ins (host-side, capture-safe).
    static bool fused_ok = [] {
        return hipFuncSetAttribute(reinterpret_cast<const void*>(gemm_fused),
                                   hipFuncAttributeMaxDynamicSharedMemorySize,
                                   131072) == hipSuccess;
    }();
    static bool lds128_ok = [] {
        return hipFuncSetAttribute(reinterpret_cast<const void*>(gemm_8phase),
                                   hipFuncAttributeMaxDynamicSharedMemorySize,
                                   131072) == hipSuccess;
    }();

    const size_t A_bytes  = (size_t)M_DIM * K_DIM * 2;            // 64 MB
    const size_t W_bytes  = (size_t)N_DIM * K_DIM * 2;            // 2 MB
    const size_t C_bytes  = (size_t)M_DIM * N_DIM * 2;            // 64 MB
    const size_t cr_bytes = (size_t)B_DIM * NCHUNK * N_DIM * 4;   // 1 MB
    const size_t need_new  = W_bytes + C_bytes + cr_bytes;        // ~67 MB
    const size_t need_mid  = A_bytes + W_bytes;
    const size_t need_full = A_bytes + W_bytes + C_bytes + cr_bytes;
    const int scan_threads = B_DIM * NCHUNK * N_DIM / 2;          // 131072

    if (fused_ok && ws_size >= need_new) {
        unsigned short* Wbf = (unsigned short*)d_ws;
        unsigned short* Cbf = (unsigned short*)((char*)d_ws + W_bytes);
        float* carry = (float*)((char*)d_ws + W_bytes + C_bytes);
        cast_f32_bf16_x8<<<(N_DIM * K_DIM / 8 + 255) / 256, 256, 0, stream>>>(Wt, Wbf, N_DIM * K_DIM / 8);
        gemm_fused<<<dim3(4, 128), 512, 131072, stream>>>(X, Wbf, bias, Cbf);
        scan_carry2<<<scan_threads / 256, 256, 0, stream>>>((const uint32*)Cbf, decay, carry);
        scan_apply2<<<scan_threads / 256, 256, 0, stream>>>((const uint32*)Cbf, decay, carry, out);
    } else if (lds128_ok && ws_size >= need_full) {
        unsigned short* Abf = (unsigned short*)d_ws;
        unsigned short* Wbf = (unsigned short*)((char*)d_ws + A_bytes);
        unsigned short* Cbf = (unsigned short*)((char*)d_ws + A_bytes + W_bytes);
        float* carry = (float*)((char*)d_ws + A_bytes + W_bytes + C_bytes);
        cast_f32_bf16_x8<<<(M_DIM * K_DIM / 8 + 255) / 256, 256, 0, stream>>>(X, Abf, M_DIM * K_DIM / 8);
        cast_f32_bf16_x8<<<(N_DIM * K_DIM / 8 + 255) / 256, 256, 0, stream>>>(Wt, Wbf, N_DIM * K_DIM / 8);
        gemm_8phase<<<dim3(4, 128), 512, 131072, stream>>>(Abf, Wbf, bias, Cbf);
        scan_carry2<<<scan_threads / 256, 256, 0, stream>>>((const uint32*)Cbf, decay, carry);
        scan_apply2<<<scan_threads / 256, 256, 0, stream>>>((const uint32*)Cbf, decay, carry, out);
    } else if (ws_size >= need_mid) {
        unsigned short* Abf = (unsigned short*)d_ws;
        unsigned short* Wbf = (unsigned short*)((char*)d_ws + A_bytes);
        cast_f32_bf16_x8<<<(M_DIM * K_DIM / 8 + 255) / 256, 256, 0, stream>>>(X, Abf, M_DIM * K_DIM / 8);
        cast_f32_bf16_x8<<<(N_DIM * K_DIM / 8 + 255) / 256, 256, 0, stream>>>(Wt, Wbf, N_DIM * K_DIM / 8);
        gemm_mfma<<<dim3(N_DIM / 128, M_DIM / 128), 256, 0, stream>>>(Abf, Wbf, bias, nullptr, out);
        scan_f32_inplace<<<512, 64, 0, stream>>>(out, decay);
    } else {
        gemm_naive<<<dim3(N_DIM / 16, M_DIM / 16), dim3(16, 16), 0, stream>>>(X, Wt, bias, out);
        scan_f32_inplace<<<512, 64, 0, stream>>>(out, decay);
    }
}

// Round 7
// 149.087 us; speedup vs baseline: 1.1722x; 1.0318x over previous
//
#include <hip/hip_runtime.h>

// Problem constants: B=32, T=1024, IN=1024, OUT=1024
// M = B*T = 32768, K = IN = 1024, N = OUT = 1024
#define M_DIM 32768
#define N_DIM 1024
#define K_DIM 1024
#define T_DIM 1024
#define B_DIM 32
#define NCHUNK 8
#define CHUNK_T 128   // T_DIM / NCHUNK

typedef unsigned int uint32;
typedef __attribute__((ext_vector_type(8))) short short8;       // 8 bf16 (MFMA A/B frag)
typedef __attribute__((ext_vector_type(8))) unsigned short ushort8v;
typedef __attribute__((ext_vector_type(4))) float floatx4;      // MFMA C/D frag

__device__ __forceinline__ unsigned short f2bf(float f) {
    uint32 u = __float_as_uint(f);
    uint32 r = u + 0x7fffu + ((u >> 16) & 1u);
    return (unsigned short)(r >> 16);
}

__device__ __forceinline__ void async_load16(const void* g, void* s) {
    __builtin_amdgcn_global_load_lds(
        (const __attribute__((address_space(1))) void*)g,
        (__attribute__((address_space(3))) void*)s,
        16, 0, 0);
}

// ---- shared schedule macros ------------------------------------------------
#define FENCE  asm volatile("" ::: "memory")
#define BAR    __builtin_amdgcn_s_barrier()
#define LGKM0  asm volatile("s_waitcnt lgkmcnt(0)" ::: "memory")
#define SCHED0 __builtin_amdgcn_sched_barrier(0)

// B half-tile JH of K-tile T -> buf PB (R2 pattern, measured conflict-free).
#define STAGE_B(JH, T, PB) do {                                              \
        size_t kof_ = (size_t)(T) * 64 + sc8;                                \
        _Pragma("unroll") for (int q_ = 0; q_ < 2; ++q_) {                   \
            int br_ = (q_ * 2 + (tid >> 8)) * 64 + (JH) * 32 + (t3 & 31);    \
            int dr_ = (q_ * 2 + (wid >> 2)) * 64 + (JH) * 32 + (wid & 3) * 8;\
            async_load16(Bw + (size_t)(bn0 + br_) * K_DIM + kof_,            \
                         smem + (PB) * 32768 + 16384 + dr_ * 64);            \
        } } while (0)

// Fragment loads (R2 pattern, measured conflict-free).
#define LD_A8(IH) do {                                                       \
        const unsigned short* As_ = smem + pb * 32768;                       \
        _Pragma("unroll") for (int ii = 0; ii < 4; ++ii) {                   \
            int r_ = wm * 128 + (IH) * 64 + ii * 16 + l15;                   \
            _Pragma("unroll") for (int ks = 0; ks < 2; ++ks) {               \
                int c_ = ks * 4 + quad;                                      \
                af[ii][ks] = *(const short8*)&As_[r_ * 64 +                  \
                                                 ((c_ ^ (l15 & 7)) * 8)];    \
            } } } while (0)
#define LD_B8(JH) do {                                                       \
        const unsigned short* Bs_ = smem + pb * 32768 + 16384;               \
        _Pragma("unroll") for (int jj = 0; jj < 2; ++jj) {                   \
            int r_ = wn * 64 + ((JH) * 2 + jj) * 16 + l15;                   \
            _Pragma("unroll") for (int ks = 0; ks < 2; ++ks) {               \
                int c_ = ks * 4 + quad;                                      \
                bfr[(JH) * 2 + jj][ks] = *(const short8*)&Bs_[r_ * 64 +      \
                                                 ((c_ ^ (l15 & 7)) * 8)];    \
            } } } while (0)
#define MM8(IH, JH) do {                                                     \
        __builtin_amdgcn_s_setprio(1);                                       \
        _Pragma("unroll") for (int ii = 0; ii < 4; ++ii)                     \
        _Pragma("unroll") for (int jj = 0; jj < 2; ++jj)                     \
        _Pragma("unroll") for (int ks = 0; ks < 2; ++ks)                     \
            acc[(IH) * 4 + ii][(JH) * 2 + jj] =                              \
                __builtin_amdgcn_mfma_f32_16x16x32_bf16(                     \
                    af[ii][ks], bfr[(JH) * 2 + jj][ks],                      \
                    acc[(IH) * 4 + ii][(JH) * 2 + jj], 0, 0, 0);             \
        __builtin_amdgcn_s_setprio(0);                                       \
    } while (0)

// ---------------------------------------------------------------------------
// fp32 -> bf16 cast, 8 elems/thread (16B store).
// ---------------------------------------------------------------------------
__global__ void cast_f32_bf16_x8(const float* __restrict__ src,
                                 unsigned short* __restrict__ dst, int n8) {
    int i = blockIdx.x * blockDim.x + threadIdx.x;
    if (i < n8) {
        const float4* s4 = (const float4*)src;
        float4 v0 = s4[(size_t)i * 2];
        float4 v1 = s4[(size_t)i * 2 + 1];
        ushort8v o;
        o[0] = f2bf(v0.x); o[1] = f2bf(v0.y); o[2] = f2bf(v0.z); o[3] = f2bf(v0.w);
        o[4] = f2bf(v1.x); o[5] = f2bf(v1.y); o[6] = f2bf(v1.z); o[7] = f2bf(v1.w);
        ((ushort8v*)dst)[i] = o;
    }
}

// ---------------------------------------------------------------------------
// MAIN GEMM (R2-verified 8-phase 256x256/BK=64, counted vmcnt(6)) + fused
// scan-carry epilogue.
//
// Carry fusion: the block's 256-row tile = exactly 2 scan chunks (CHUNK_T=128)
// of one batch. Wave wm-half covers one chunk; per column, local t =
// 16*i + 4*quad + r over the acc fragments. The chunk carry
//   cv = sum_t a^(127-t) * (1-a) * (acc_t + bias)
// is computed in-register: per (j,r) seed w = a^(15-4q-r) (4 select-mults),
// iterate i = 7..0 with w *= a^16 (8 FMA); quad-reduce via shfl_xor 16/32;
// bias term added once as bias*(1 - a^128). One f32 store per quad-0 lane.
// Replaces the scan_carry2 kernel (and its 64 MB C re-read) entirely.
// Carry is computed from UNROUNDED f32 acc (closer to the f32 reference than
// the old bf16-sourced carry).
// ---------------------------------------------------------------------------
__global__ __launch_bounds__(512, 2) void gemm_8phase(
    const unsigned short* __restrict__ A,   // [M, K] bf16
    const unsigned short* __restrict__ Bw,  // [N, K] bf16
    const float* __restrict__ bias,         // [N]
    const float* __restrict__ decay,        // [N]
    unsigned short* __restrict__ outBf,     // [M, N] bf16
    float* __restrict__ carry) {            // [B, NCHUNK, N]
    extern __shared__ __align__(16) unsigned short smem[];  // 131072 B

    const int tid  = threadIdx.x;
    const int lane = tid & 63;
    const int wid  = tid >> 6;
    const int l15  = lane & 15;
    const int quad = lane >> 4;
    const int wm   = wid >> 2;
    const int wn   = wid & 3;

    const int L   = blockIdx.y * gridDim.x + blockIdx.x;
    const int xcd = L & 7;
    const int s   = L >> 3;
    const int bn0 = (s & 3) * 256;
    const int bm0 = (xcd * 16 + (s >> 2)) * 256;

    const int t3  = tid >> 3;
    const int sc8 = ((tid & 7) ^ (t3 & 7)) * 8;

#define STAGE_A(IH, T, PB) do {                                              \
        size_t kof_ = (size_t)(T) * 64 + sc8;                                \
        _Pragma("unroll") for (int q_ = 0; q_ < 2; ++q_) {                   \
            int ar_ = q_ * 128 + (IH) * 64 + t3;                             \
            int dr_ = q_ * 128 + (IH) * 64 + wid * 8;                        \
            async_load16(A + (size_t)(bm0 + ar_) * K_DIM + kof_,             \
                         smem + (PB) * 32768 + dr_ * 64);                    \
        } } while (0)

    floatx4 acc[8][4];
#pragma unroll
    for (int i = 0; i < 8; ++i)
#pragma unroll
        for (int j = 0; j < 4; ++j)
            acc[i][j] = (floatx4){0.f, 0.f, 0.f, 0.f};

    short8 af[4][2];
    short8 bfr[4][2];

    const int NT = K_DIM / 64;   // 16

    STAGE_A(0, 0, 0); STAGE_A(1, 0, 0); STAGE_B(0, 0, 0); STAGE_B(1, 0, 0);
    STAGE_A(0, 1, 1); STAGE_B(1, 1, 1); STAGE_B(0, 1, 1);
    asm volatile("s_waitcnt vmcnt(6)" ::: "memory");
    FENCE; BAR;

    for (int g = 0; g < NT; ++g) {
        const int pb = g & 1;
        const int po = pb ^ 1;

        LD_A8(0); LD_B8(0);
        if (g + 1 < NT) STAGE_A(1, g + 1, po);
        FENCE; BAR; LGKM0; SCHED0;
        MM8(0, 0);
        SCHED0; FENCE; BAR;

        LD_B8(1);
        if (g + 2 < NT) STAGE_A(0, g + 2, pb);
        FENCE; BAR; LGKM0; SCHED0;
        MM8(0, 1);
        SCHED0; FENCE; BAR;

        LD_A8(1);
        if (g + 2 < NT) STAGE_B(1, g + 2, pb);
        FENCE; BAR; LGKM0; SCHED0;
        MM8(1, 0);
        SCHED0; FENCE; BAR;

        if (g + 2 < NT) STAGE_B(0, g + 2, pb);
        if (g < NT - 2) {
            asm volatile("s_waitcnt vmcnt(6)" ::: "memory");
        } else if (g == NT - 2) {
            asm volatile("s_waitcnt vmcnt(0)" ::: "memory");
        }
        FENCE; BAR; LGKM0; SCHED0;
        MM8(1, 1);
        SCHED0; FENCE; BAR;
    }
    asm volatile("s_waitcnt vmcnt(0)" ::: "memory");

    // ---- C store (j innermost: full 128B lines, no write amplification) ----
    float bb[4];
#pragma unroll
    for (int j = 0; j < 4; ++j) bb[j] = bias[bn0 + wn * 64 + j * 16 + l15];
#pragma unroll
    for (int i = 0; i < 8; ++i) {
        int rowb = bm0 + wm * 128 + i * 16 + quad * 4;
#pragma unroll
        for (int r = 0; r < 4; ++r) {
            size_t rb = (size_t)(rowb + r) * N_DIM + bn0 + wn * 64 + l15;
#pragma unroll
            for (int j = 0; j < 4; ++j)
                outBf[rb + j * 16] = f2bf(acc[i][j][r] + bb[j]);
        }
    }

    // ---- fused carry epilogue (registers + shfl only, no barriers) --------
    {
        const int q4 = quad * 4;
        const int bchk = ((bm0 >> 10) * NCHUNK) + ((bm0 >> 7) & 7) + wm;
        float* cdst = carry + (size_t)bchk * N_DIM + bn0 + wn * 64;
#pragma unroll
        for (int j = 0; j < 4; ++j) {
            float a  = decay[bn0 + wn * 64 + j * 16 + l15];
            float a2 = a * a, a4 = a2 * a2, a8 = a4 * a4, a16 = a8 * a8;
            float S = 0.f;
#pragma unroll
            for (int r = 0; r < 4; ++r) {
                int n = 15 - q4 - r;                // seed exponent, 0..15
                float w = 1.f;
                w *= (n & 1) ? a  : 1.f;
                w *= (n & 2) ? a2 : 1.f;
                w *= (n & 4) ? a4 : 1.f;
                w *= (n & 8) ? a8 : 1.f;
                // descending i: t = 16i + q4 + r, weight a^(127-t)
#pragma unroll
                for (int ii = 0; ii < 8; ++ii) {
                    S = fmaf(w, acc[7 - ii][j][r], S);
                    w *= a16;
                }
            }
            // quad-reduction: lanes l15, +16, +32, +48 hold the 4 partials
            S += __shfl_xor(S, 16, 64);
            S += __shfl_xor(S, 32, 64);
            float a32 = a16 * a16, a64 = a32 * a32, a128 = a64 * a64;
            float cv = (1.f - a) * S + bb[j] * (1.f - a128);
            if (quad == 0) cdst[j * 16 + l15] = cv;
        }
    }
#undef STAGE_A
}

// ---------------------------------------------------------------------------
// Scan-apply: seed from carries, re-scan own chunk from bf16 C, write f32.
// ---------------------------------------------------------------------------
__global__ __launch_bounds__(256) void scan_apply2(
    const uint32* __restrict__ cur32,         // [M, N/2] (bf16 pairs)
    const float* __restrict__ decay,
    const float* __restrict__ carry,          // [B, NCHUNK, N]
    float* __restrict__ out) {                // [M, N] fp32
    int tid   = blockIdx.x * 256 + threadIdx.x;
    int o2    = tid & 511;
    int chunk = (tid >> 9) & (NCHUNK - 1);
    int b     = tid >> 12;
    int o     = o2 * 2;
    size_t base = ((size_t)b * T_DIM + (size_t)chunk * CHUNK_T) * (N_DIM / 2) + o2;
    float2 a2 = *(const float2*)&decay[o];
    float a0 = a2.x, a1 = a2.y;
    float c0 = 1.f - a0, c1 = 1.f - a1;

    float A0 = a0, A1 = a1;
#pragma unroll
    for (int i = 0; i < 7; ++i) { A0 *= A0; A1 *= A1; }   // a^128

    float u0 = 0.f, u1 = 0.f;
    const float* cb = carry + (size_t)b * NCHUNK * N_DIM + o;
    for (int i = 0; i < chunk; ++i) {         // wave-uniform trip count
        float2 cv = *(const float2*)&cb[(size_t)i * N_DIM];
        u0 = cv.x + A0 * u0;
        u1 = cv.y + A1 * u1;
    }

    float2* out2 = (float2*)out;
    size_t obase = ((size_t)b * T_DIM + (size_t)chunk * CHUNK_T) * (N_DIM / 2) + o2;
    for (int t0 = 0; t0 < CHUNK_T; t0 += 32) {
        uint32 x[32];
#pragma unroll
        for (int k = 0; k < 32; ++k)
            x[k] = cur32[base + (size_t)(t0 + k) * (N_DIM / 2)];
#pragma unroll
        for (int k = 0; k < 32; ++k) {
            float lo = __uint_as_float(x[k] << 16);
            float hi = __uint_as_float(x[k] & 0xffff0000u);
            u0 = a0 * u0 + c0 * lo;
            u1 = a1 * u1 + c1 * hi;
            out2[obase + (size_t)(t0 + k) * (N_DIM / 2)] = (float2){u0, u1};
        }
    }
}

// ---------------------------------------------------------------------------
// Fallbacks (only used if workspace too small for the bf16 path)
// ---------------------------------------------------------------------------
__global__ void scan_f32_inplace(float* __restrict__ buf,
                                 const float* __restrict__ decay) {
    int tid = blockIdx.x * 64 + threadIdx.x;
    int o = tid & (N_DIM - 1);
    size_t base = ((size_t)(tid >> 10) << 20) + o;
    float a = decay[o];
    float c = 1.f - a;
    float u = 0.f;
    for (int t0 = 0; t0 < 1024; t0 += 16) {
        float x[16];
#pragma unroll
        for (int k = 0; k < 16; ++k)
            x[k] = buf[base + (size_t)(t0 + k) * N_DIM];
#pragma unroll
        for (int k = 0; k < 16; ++k) {
            u = a * u + c * x[k];
            buf[base + (size_t)(t0 + k) * N_DIM] = u;
        }
    }
}

__global__ __launch_bounds__(256) void gemm_mfma(
    const unsigned short* __restrict__ A,
    const unsigned short* __restrict__ Bw,
    const float* __restrict__ bias,
    unsigned short* outBf,
    float* outF) {
    __shared__ unsigned short As[128 * 64];
    __shared__ unsigned short Bs[128 * 64];

    const int tid  = threadIdx.x;
    const int lane = tid & 63;
    const int wid  = tid >> 6;
    const int l15  = lane & 15;
    const int quad = lane >> 4;
    const int wm   = wid >> 1;
    const int wn   = wid & 1;

    const int L    = blockIdx.y * gridDim.x + blockIdx.x;
    const int xcd  = L & 7;
    const int s    = L >> 3;
    const int bn0  = (s & 7) * 128;
    const int bm0  = (xcd * 32 + (s >> 3)) * 128;

    floatx4 acc[4][4];
#pragma unroll
    for (int i = 0; i < 4; ++i)
#pragma unroll
        for (int j = 0; j < 4; ++j)
            acc[i][j] = (floatx4){0.f, 0.f, 0.f, 0.f};

    for (int kt = 0; kt < K_DIM / 64; ++kt) {
        const int k0 = kt * 64;
#pragma unroll
        for (int q = 0; q < 4; ++q) {
            int slot = q * 256 + tid;
            int row  = slot >> 3;
            int chq  = slot & 7;
            int scq  = chq ^ (row & 7);
            async_load16(A + (size_t)(bm0 + row) * K_DIM + k0 + scq * 8,
                         &As[(q * 256 + wid * 64) * 8]);
        }
#pragma unroll
        for (int q = 0; q < 4; ++q) {
            int slot = q * 256 + tid;
            int row  = slot >> 3;
            int chq  = slot & 7;
            int scq  = chq ^ (row & 7);
            async_load16(Bw + (size_t)(bn0 + row) * K_DIM + k0 + scq * 8,
                         &Bs[(q * 256 + wid * 64) * 8]);
        }
        __syncthreads();

#pragma unroll
        for (int ks = 0; ks < 2; ++ks) {
            short8 af[4], bfr[4];
#pragma unroll
            for (int i = 0; i < 4; ++i) {
                int r = wm * 64 + i * 16 + l15;
                int c = ks * 4 + quad;
                af[i] = *(const short8*)&As[r * 64 + ((c ^ (r & 7)) * 8)];
            }
#pragma unroll
            for (int j = 0; j < 4; ++j) {
                int r = wn * 64 + j * 16 + l15;
                int c = ks * 4 + quad;
                bfr[j] = *(const short8*)&Bs[r * 64 + ((c ^ (r & 7)) * 8)];
            }
#pragma unroll
            for (int i = 0; i < 4; ++i)
#pragma unroll
                for (int j = 0; j < 4; ++j)
                    acc[i][j] = __builtin_amdgcn_mfma_f32_16x16x32_bf16(
                        af[i], bfr[j], acc[i][j], 0, 0, 0);
        }
        __syncthreads();
    }

#pragma unroll
    for (int j = 0; j < 4; ++j) {
        int col = bn0 + wn * 64 + j * 16 + l15;
        float bb = bias[col];
#pragma unroll
        for (int i = 0; i < 4; ++i) {
            int rowb = bm0 + wm * 64 + i * 16 + quad * 4;
#pragma unroll
            for (int r = 0; r < 4; ++r) {
                float v = acc[i][j][r] + bb;
                size_t idx = (size_t)(rowb + r) * N_DIM + col;
                if (outBf) outBf[idx] = f2bf(v);
                else       outF[idx]  = v;
            }
        }
    }
}

__global__ void gemm_naive(const float* __restrict__ X, const float* __restrict__ W,
                           const float* __restrict__ bias, float* __restrict__ out) {
    __shared__ float As[16][17], Bs[16][17];
    int tx = threadIdx.x, ty = threadIdx.y;
    int m0 = blockIdx.y * 16, n0 = blockIdx.x * 16;
    float acc = 0.f;
    for (int k0 = 0; k0 < K_DIM; k0 += 16) {
        As[ty][tx] = X[(size_t)(m0 + ty) * K_DIM + k0 + tx];
        Bs[ty][tx] = W[(size_t)(n0 + ty) * K_DIM + k0 + tx];
        __syncthreads();
#pragma unroll
        for (int kk = 0; kk < 16; ++kk) acc += As[ty][kk] * Bs[tx][kk];
        __syncthreads();
    }
    out[(size_t)(m0 + ty) * N_DIM + n0 + tx] = acc + bias[n0 + tx];
}

// ---------------------------------------------------------------------------
extern "C" void kernel_launch(void* const* d_in, const int* in_sizes, int n_in,
                              void* d_out, int out_size, void* d_ws, size_t ws_size,
                              hipStream_t stream) {
    const float* X     = (const float*)d_in[0];  // [B,T,IN]  = [M,K]
    const float* Wt    = (const float*)d_in[1];  // [OUT,IN]  = [N,K]
    const float* bias  = (const float*)d_in[2];  // [OUT]
    const float* decay = (const float*)d_in[3];  // [OUT]
    float* out = (float*)d_out;                  // [B,T,OUT] = [M,N]

    // One-time LDS opt-in (host-side, capture-safe).
    static bool lds128_ok = [] {
        return hipFuncSetAttribute(reinterpret_cast<const void*>(gemm_8phase),
                                   hipFuncAttributeMaxDynamicSharedMemorySize,
                                   131072) == hipSuccess;
    }();

    const size_t A_bytes  = (size_t)M_DIM * K_DIM * 2;            // 64 MB
    const size_t W_bytes  = (size_t)N_DIM * K_DIM * 2;            // 2 MB
    const size_t C_bytes  = (size_t)M_DIM * N_DIM * 2;            // 64 MB
    const size_t cr_bytes = (size_t)B_DIM * NCHUNK * N_DIM * 4;   // 1 MB
    const size_t need_mid  = A_bytes + W_bytes;
    const size_t need_full = A_bytes + W_bytes + C_bytes + cr_bytes;
    const int scan_threads = B_DIM * NCHUNK * N_DIM / 2;          // 131072

    if (lds128_ok && ws_size >= need_full) {
        unsigned short* Abf = (unsigned short*)d_ws;
        unsigned short* Wbf = (unsigned short*)((char*)d_ws + A_bytes);
        unsigned short* Cbf = (unsigned short*)((char*)d_ws + A_bytes + W_bytes);
        float* carry = (float*)((char*)d_ws + A_bytes + W_bytes + C_bytes);
        cast_f32_bf16_x8<<<(M_DIM * K_DIM / 8 + 255) / 256, 256, 0, stream>>>(X, Abf, M_DIM * K_DIM / 8);
        cast_f32_bf16_x8<<<(N_DIM * K_DIM / 8 + 255) / 256, 256, 0, stream>>>(Wt, Wbf, N_DIM * K_DIM / 8);
        gemm_8phase<<<dim3(4, 128), 512, 131072, stream>>>(Abf, Wbf, bias, decay, Cbf, carry);
        scan_apply2<<<scan_threads / 256, 256, 0, stream>>>((const uint32*)Cbf, decay, carry, out);
    } else if (ws_size >= need_mid) {
        unsigned short* Abf = (unsigned short*)d_ws;
        unsigned short* Wbf = (unsigned short*)((char*)d_ws + A_bytes);
        cast_f32_bf16_x8<<<(M_DIM * K_DIM / 8 + 255) / 256, 256, 0, stream>>>(X, Abf, M_DIM * K_DIM / 8);
        cast_f32_bf16_x8<<<(N_DIM * K_DIM / 8 + 255) / 256, 256, 0, stream>>>(Wt, Wbf, N_DIM * K_DIM / 8);
        gemm_mfma<<<dim3(N_DIM / 128, M_DIM / 128), 256, 0, stream>>>(Abf, Wbf, bias, nullptr, out);
        scan_f32_inplace<<<512, 64, 0, stream>>>(out, decay);
    } else {
        gemm_naive<<<dim3(N_DIM / 16, M_DIM / 16), dim3(16, 16), 0, stream>>>(X, Wt, bias, out);
        scan_f32_inplace<<<512, 64, 0, stream>>>(out, decay);
    }
}

// Round 9
// 133.535 us; speedup vs baseline: 1.3088x; 1.1165x over previous
//
#include <hip/hip_runtime.h>

// Problem constants: B=32, T=1024, IN=1024, OUT=1024
// M = B*T = 32768, K = IN = 1024, N = OUT = 1024
#define M_DIM 32768
#define N_DIM 1024
#define K_DIM 1024
#define T_DIM 1024
#define B_DIM 32
#define NCHUNK 8
#define CHUNK_T 128   // T_DIM / NCHUNK

typedef unsigned int uint32;
typedef __attribute__((ext_vector_type(8))) short short8;       // 8 bf16 (MFMA A/B frag)
typedef __attribute__((ext_vector_type(8))) unsigned short ushort8v;
typedef __attribute__((ext_vector_type(4))) float floatx4;      // MFMA C/D frag + asm loads

__device__ __forceinline__ unsigned short f2bf(float f) {
    uint32 u = __float_as_uint(f);
    uint32 r = u + 0x7fffu + ((u >> 16) & 1u);
    return (unsigned short)(r >> 16);
}

__device__ __forceinline__ void async_load16(const void* g, void* s) {
    __builtin_amdgcn_global_load_lds(
        (const __attribute__((address_space(1))) void*)g,
        (__attribute__((address_space(3))) void*)s,
        16, 0, 0);
}

// 8 f32 -> short8 of bf16 via v_cvt_pk_bf16_f32 (RNE, same as f2bf).
// Operands are ext_vector elements (scalars) — NEVER HIP struct float4 in
// asm "v" operands (R4 lesson).
__device__ __forceinline__ short8 pk8(floatx4 a, floatx4 b) {
    union { short8 s; uint32 d[4]; } u;
    asm("v_cvt_pk_bf16_f32 %0, %1, %2" : "=v"(u.d[0]) : "v"(a[0]), "v"(a[1]));
    asm("v_cvt_pk_bf16_f32 %0, %1, %2" : "=v"(u.d[1]) : "v"(a[2]), "v"(a[3]));
    asm("v_cvt_pk_bf16_f32 %0, %1, %2" : "=v"(u.d[2]) : "v"(b[0]), "v"(b[1]));
    asm("v_cvt_pk_bf16_f32 %0, %1, %2" : "=v"(u.d[3]) : "v"(b[2]), "v"(b[3]));
    return u.s;
}

// ---- shared schedule macros ------------------------------------------------
#define FENCE  asm volatile("" ::: "memory")
#define BAR    __builtin_amdgcn_s_barrier()
#define LGKM0  asm volatile("s_waitcnt lgkmcnt(0)" ::: "memory")
#define SCHED0 __builtin_amdgcn_sched_barrier(0)
#define VMW(N) asm volatile("s_waitcnt vmcnt(" #N ")" ::: "memory")

// B half-tile JH of K-tile T -> buf PB (R2 pattern, measured conflict-free).
#define STAGE_B(JH, T, PB) do {                                              \
        size_t kof_ = (size_t)(T) * 64 + sc8;                                \
        _Pragma("unroll") for (int q_ = 0; q_ < 2; ++q_) {                   \
            int br_ = (q_ * 2 + (tid >> 8)) * 64 + (JH) * 32 + (t3 & 31);    \
            int dr_ = (q_ * 2 + (wid >> 2)) * 64 + (JH) * 32 + (wid & 3) * 8;\
            async_load16(Bw + (size_t)(bn0 + br_) * K_DIM + kof_,            \
                         smem + (PB) * 32768 + 16384 + dr_ * 64);            \
        } } while (0)

// Fragment loads (R2 pattern, measured conflict-free).
#define LD_A8(IH) do {                                                       \
        const unsigned short* As_ = smem + pb * 32768;                       \
        _Pragma("unroll") for (int ii = 0; ii < 4; ++ii) {                   \
            int r_ = wm * 128 + (IH) * 64 + ii * 16 + l15;                   \
            _Pragma("unroll") for (int ks = 0; ks < 2; ++ks) {               \
                int c_ = ks * 4 + quad;                                      \
                af[ii][ks] = *(const short8*)&As_[r_ * 64 +                  \
                                                 ((c_ ^ (l15 & 7)) * 8)];    \
            } } } while (0)
#define LD_B8(JH) do {                                                       \
        const unsigned short* Bs_ = smem + pb * 32768 + 16384;               \
        _Pragma("unroll") for (int jj = 0; jj < 2; ++jj) {                   \
            int r_ = wn * 64 + ((JH) * 2 + jj) * 16 + l15;                   \
            _Pragma("unroll") for (int ks = 0; ks < 2; ++ks) {               \
                int c_ = ks * 4 + quad;                                      \
                bfr[(JH) * 2 + jj][ks] = *(const short8*)&Bs_[r_ * 64 +      \
                                                 ((c_ ^ (l15 & 7)) * 8)];    \
            } } } while (0)
#define MM8(IH, JH) do {                                                     \
        __builtin_amdgcn_s_setprio(1);                                       \
        _Pragma("unroll") for (int ii = 0; ii < 4; ++ii)                     \
        _Pragma("unroll") for (int jj = 0; jj < 2; ++jj)                     \
        _Pragma("unroll") for (int ks = 0; ks < 2; ++ks)                     \
            acc[(IH) * 4 + ii][(JH) * 2 + jj] =                              \
                __builtin_amdgcn_mfma_f32_16x16x32_bf16(                     \
                    af[ii][ks], bfr[(JH) * 2 + jj][ks],                      \
                    acc[(IH) * 4 + ii][(JH) * 2 + jj], 0, 0, 0);             \
        __builtin_amdgcn_s_setprio(0);                                       \
    } while (0)

// A reg-staging (cast-fused). Slot P holds f32 pair for row quarter P.
// RULE (R8 crash): the read of ar[2P..] (AWRITE) must PRECEDE any AISSUE
// redefinition of the same slot in program order, and the old load must be
// vmcnt-drained before the read. Never leave an in-flight load's dest
// registers reader-less.
#define AISSUE(P, T) do {                                                    \
        const float* p_ = abase[P] + (T) * 64;                               \
        asm volatile("global_load_dwordx4 %0, %1, off"                       \
                     : "=&v"(ar[2 * (P)]) : "v"(p_));                        \
        asm volatile("global_load_dwordx4 %0, %1, off offset:16"             \
                     : "=&v"(ar[2 * (P) + 1]) : "v"(p_));                    \
    } while (0)
// Convert + swizzled ds_write into buf PBDST (content layout == DMA layout:
// LDS chunk position p of row r holds global chunk p ^ (r&7)).
#define AWRITE(P, PBDST) do {                                                \
        int row_ = (P) * 64 + (tid >> 3);                                    \
        int cs_  = (tid & 7) ^ (row_ & 7);                                   \
        *(short8*)&smem[(PBDST) * 32768 + row_ * 64 + cs_ * 8] =             \
            pk8(ar[2 * (P)], ar[2 * (P) + 1]);                               \
    } while (0)

// ---------------------------------------------------------------------------
// fp32 -> bf16 cast, 8 elems/thread (16B store). W (2 MB) on main path;
// A-cast only in fallback.
// ---------------------------------------------------------------------------
__global__ void cast_f32_bf16_x8(const float* __restrict__ src,
                                 unsigned short* __restrict__ dst, int n8) {
    int i = blockIdx.x * blockDim.x + threadIdx.x;
    if (i < n8) {
        const float4* s4 = (const float4*)src;
        float4 v0 = s4[(size_t)i * 2];
        float4 v1 = s4[(size_t)i * 2 + 1];
        ushort8v o;
        o[0] = f2bf(v0.x); o[1] = f2bf(v0.y); o[2] = f2bf(v0.z); o[3] = f2bf(v0.w);
        o[4] = f2bf(v1.x); o[5] = f2bf(v1.y); o[6] = f2bf(v1.z); o[7] = f2bf(v1.w);
        ((ushort8v*)dst)[i] = o;
    }
}

// ---------------------------------------------------------------------------
// MAIN GEMM: 8-phase 256x256/BK=64, A-cast fused via reg-staging.
//
// Phase = {ds_reads; VMW(N); BAR; lgkm0; MFMA; AWRITE(P)->buf po;
//          AISSUE(P, g+2) [+STAGE_B]; BAR}.
// AWRITE after MFMA (hides ds_write latency: drained by NEXT phase's lgkm0,
// covered by a barrier + MFMA by then — fixes R5's 130us). AISSUE strictly
// AFTER AWRITE (read-before-redefine — fixes R8's register-clobber crash).
//
// vmcnt ledger (issues AFTER each phase's VMW; 12 ops/tile:
// p0:+2(a0) p1:+4(b0,a1) p2:+2(a2) p3:+4(b1,a3)):
//   entering each phase outstanding = 12; VMW = 10/8/10/8 drains exactly
//   {a0}/{b0,a1}/{a2}/{b1,a3} of tile g+1 -> AWRITE operands + B residency.
//   Outstanding never < 8. Prologue: VMW(4) [A(0)] -> AWRITE buf0 -> issue
//   tile 1 (12 ops) -> VMW(12) [B(0)]. Tail tile 14: 10/6/4/0 (no issues,
//   no redefs). Tile 15: compute only.
// Cross-wave: AWRITE at pP(g) drained by writer's lgkm0 at pP+1(g), read at
// pP(g+1) or later (>= 2 barriers). STAGE_B targets regions read >=1 barrier
// earlier (R2's proven plan).
// Carry epilogue: R7-verified in-register chunk-carry (replaces scan_carry2).
// ---------------------------------------------------------------------------
__global__ __launch_bounds__(512, 2) void gemm_fused2(
    const float* __restrict__ X32,          // [M, K] fp32
    const unsigned short* __restrict__ Bw,  // [N, K] bf16
    const float* __restrict__ bias,         // [N]
    const float* __restrict__ decay,        // [N]
    unsigned short* __restrict__ outBf,     // [M, N] bf16
    float* __restrict__ carry) {            // [B, NCHUNK, N]
    extern __shared__ __align__(16) unsigned short smem[];  // 131072 B

    const int tid  = threadIdx.x;
    const int lane = tid & 63;
    const int wid  = tid >> 6;      // 0..7
    const int l15  = lane & 15;
    const int quad = lane >> 4;
    const int wm   = wid >> 2;      // 0..1
    const int wn   = wid & 3;       // 0..3

    // XCD-aware remap: 512 blocks; xcd owns 16 M-panels, 4 N-tiles each.
    const int L   = blockIdx.y * gridDim.x + blockIdx.x;   // 0..511
    const int xcd = L & 7;
    const int s   = L >> 3;
    const int bn0 = (s & 3) * 256;
    const int bm0 = (xcd * 16 + (s >> 2)) * 256;

    const int t3  = tid >> 3;                               // 0..63
    const int sc8 = ((tid & 7) ^ (t3 & 7)) * 8;             // B-staging swizzle

    // A-source base per row-quarter (thread-fixed; +T*64 floats per K-tile).
    const float* abase[4];
#pragma unroll
    for (int p = 0; p < 4; ++p)
        abase[p] = X32 + (size_t)(bm0 + p * 64 + (tid >> 3)) * K_DIM + (tid & 7) * 8;

    floatx4 acc[8][4];
#pragma unroll
    for (int i = 0; i < 8; ++i)
#pragma unroll
        for (int j = 0; j < 4; ++j)
            acc[i][j] = (floatx4){0.f, 0.f, 0.f, 0.f};

    short8 af[4][2];
    short8 bfr[4][2];
    floatx4 ar[8];                   // in-flight A f32 (literal indices only)

    // Prologue: tile 0 loads (8 A + 4 B), drain A, write buf0; issue tile 1
    // in steady age-order (a0,b0,a1,a2,b1,a3); drain tile-0 B; publish.
    AISSUE(0, 0); AISSUE(1, 0); AISSUE(2, 0); AISSUE(3, 0);
    STAGE_B(0, 0, 0); STAGE_B(1, 0, 0);
    VMW(4); SCHED0;
    AWRITE(0, 0); AWRITE(1, 0); AWRITE(2, 0); AWRITE(3, 0);
    AISSUE(0, 1); STAGE_B(0, 1, 1); AISSUE(1, 1); AISSUE(2, 1);
    STAGE_B(1, 1, 1); AISSUE(3, 1);
    LGKM0; VMW(12); FENCE; BAR;

    // Main loop: tiles 0..13 (issue gens 2..15, all valid).
#define TILE_MAIN(G) do {                                                    \
        const int pb = (G) & 1;                                              \
        const int po = pb ^ 1;                                               \
        LD_A8(0); LD_B8(0);                                                  \
        VMW(10); FENCE; BAR; LGKM0; SCHED0;                                  \
        MM8(0, 0);                                                           \
        SCHED0; AWRITE(0, po); AISSUE(0, (G) + 2); FENCE; BAR;               \
        LD_B8(1);                                                            \
        VMW(8); FENCE; BAR; LGKM0; SCHED0;                                   \
        MM8(0, 1);                                                           \
        SCHED0; AWRITE(1, po); STAGE_B(0, (G) + 2, pb); AISSUE(1, (G) + 2);  \
        FENCE; BAR;                                                          \
        LD_A8(1);                                                            \
        VMW(10); FENCE; BAR; LGKM0; SCHED0;                                  \
        MM8(1, 0);                                                           \
        SCHED0; AWRITE(2, po); AISSUE(2, (G) + 2); FENCE; BAR;               \
        VMW(8); FENCE; BAR; LGKM0; SCHED0;                                   \
        MM8(1, 1);                                                           \
        SCHED0; AWRITE(3, po); STAGE_B(1, (G) + 2, pb); AISSUE(3, (G) + 2);  \
        FENCE; BAR;                                                          \
    } while (0)

    for (int g = 0; g < 14; ++g) TILE_MAIN(g);
#undef TILE_MAIN

    // Tile 14 (pb=0): no issues, no redefs; tail VMW 10/6/4/0; AWRITEs fill
    // tile 15 -> buf1.
    {
        const int pb = 0;
        LD_A8(0); LD_B8(0);
        VMW(10); FENCE; BAR; LGKM0; SCHED0;
        MM8(0, 0);
        SCHED0; AWRITE(0, 1); FENCE; BAR;
        LD_B8(1);
        VMW(6); FENCE; BAR; LGKM0; SCHED0;
        MM8(0, 1);
        SCHED0; AWRITE(1, 1); FENCE; BAR;
        LD_A8(1);
        VMW(4); FENCE; BAR; LGKM0; SCHED0;
        MM8(1, 0);
        SCHED0; AWRITE(2, 1); FENCE; BAR;
        VMW(0); FENCE; BAR; LGKM0; SCHED0;
        MM8(1, 1);
        SCHED0; AWRITE(3, 1); FENCE; BAR;
    }
    // Tile 15 (pb=1): compute only (vmcnt == 0).
    {
        const int pb = 1;
        LD_A8(0); LD_B8(0); FENCE; BAR; LGKM0; SCHED0; MM8(0, 0); SCHED0; FENCE; BAR;
        LD_B8(1);           FENCE; BAR; LGKM0; SCHED0; MM8(0, 1); SCHED0; FENCE; BAR;
        LD_A8(1);           FENCE; BAR; LGKM0; SCHED0; MM8(1, 0); SCHED0; FENCE; BAR;
                            FENCE; BAR; LGKM0; SCHED0; MM8(1, 1); SCHED0; FENCE; BAR;
    }

    // ---- C store (j innermost: full 128B lines, no write amplification) ----
    float bb[4];
#pragma unroll
    for (int j = 0; j < 4; ++j) bb[j] = bias[bn0 + wn * 64 + j * 16 + l15];
#pragma unroll
    for (int i = 0; i < 8; ++i) {
        int rowb = bm0 + wm * 128 + i * 16 + quad * 4;
#pragma unroll
        for (int r = 0; r < 4; ++r) {
            size_t rb = (size_t)(rowb + r) * N_DIM + bn0 + wn * 64 + l15;
#pragma unroll
            for (int j = 0; j < 4; ++j)
                outBf[rb + j * 16] = f2bf(acc[i][j][r] + bb[j]);
        }
    }

    // ---- fused carry epilogue (R7-verified; registers + shfl, no barriers) --
    {
        const int q4 = quad * 4;
        const int bchk = ((bm0 >> 10) * NCHUNK) + ((bm0 >> 7) & 7) + wm;
        float* cdst = carry + (size_t)bchk * N_DIM + bn0 + wn * 64;
#pragma unroll
        for (int j = 0; j < 4; ++j) {
            float a  = decay[bn0 + wn * 64 + j * 16 + l15];
            float a2 = a * a, a4 = a2 * a2, a8 = a4 * a4, a16 = a8 * a8;
            float S = 0.f;
#pragma unroll
            for (int r = 0; r < 4; ++r) {
                int n = 15 - q4 - r;                // seed exponent, 0..15
                float w = 1.f;
                w *= (n & 1) ? a  : 1.f;
                w *= (n & 2) ? a2 : 1.f;
                w *= (n & 4) ? a4 : 1.f;
                w *= (n & 8) ? a8 : 1.f;
#pragma unroll
                for (int ii = 0; ii < 8; ++ii) {
                    S = fmaf(w, acc[7 - ii][j][r], S);
                    w *= a16;
                }
            }
            S += __shfl_xor(S, 16, 64);
            S += __shfl_xor(S, 32, 64);
            float a32 = a16 * a16, a64 = a32 * a32, a128 = a64 * a64;
            float cv = (1.f - a) * S + bb[j] * (1.f - a128);
            if (quad == 0) cdst[j * 16 + l15] = cv;
        }
    }
}

// ---------------------------------------------------------------------------
// R7 8-phase bf16 GEMM + fused carry — fallback (needs pre-cast A).
// ---------------------------------------------------------------------------
__global__ __launch_bounds__(512, 2) void gemm_8phase(
    const unsigned short* __restrict__ A,   // [M, K] bf16
    const unsigned short* __restrict__ Bw,  // [N, K] bf16
    const float* __restrict__ bias,         // [N]
    const float* __restrict__ decay,        // [N]
    unsigned short* __restrict__ outBf,     // [M, N] bf16
    float* __restrict__ carry) {            // [B, NCHUNK, N]
    extern __shared__ __align__(16) unsigned short smem[];  // 131072 B

    const int tid  = threadIdx.x;
    const int lane = tid & 63;
    const int wid  = tid >> 6;
    const int l15  = lane & 15;
    const int quad = lane >> 4;
    const int wm   = wid >> 2;
    const int wn   = wid & 3;

    const int L   = blockIdx.y * gridDim.x + blockIdx.x;
    const int xcd = L & 7;
    const int s   = L >> 3;
    const int bn0 = (s & 3) * 256;
    const int bm0 = (xcd * 16 + (s >> 2)) * 256;

    const int t3  = tid >> 3;
    const int sc8 = ((tid & 7) ^ (t3 & 7)) * 8;

#define STAGE_A(IH, T, PB) do {                                              \
        size_t kof_ = (size_t)(T) * 64 + sc8;                                \
        _Pragma("unroll") for (int q_ = 0; q_ < 2; ++q_) {                   \
            int ar_ = q_ * 128 + (IH) * 64 + t3;                             \
            int dr_ = q_ * 128 + (IH) * 64 + wid * 8;                        \
            async_load16(A + (size_t)(bm0 + ar_) * K_DIM + kof_,             \
                         smem + (PB) * 32768 + dr_ * 64);                    \
        } } while (0)

    floatx4 acc[8][4];
#pragma unroll
    for (int i = 0; i < 8; ++i)
#pragma unroll
        for (int j = 0; j < 4; ++j)
            acc[i][j] = (floatx4){0.f, 0.f, 0.f, 0.f};

    short8 af[4][2];
    short8 bfr[4][2];

    const int NT = K_DIM / 64;   // 16

    STAGE_A(0, 0, 0); STAGE_A(1, 0, 0); STAGE_B(0, 0, 0); STAGE_B(1, 0, 0);
    STAGE_A(0, 1, 1); STAGE_B(1, 1, 1); STAGE_B(0, 1, 1);
    asm volatile("s_waitcnt vmcnt(6)" ::: "memory");
    FENCE; BAR;

    for (int g = 0; g < NT; ++g) {
        const int pb = g & 1;
        const int po = pb ^ 1;

        LD_A8(0); LD_B8(0);
        if (g + 1 < NT) STAGE_A(1, g + 1, po);
        FENCE; BAR; LGKM0; SCHED0;
        MM8(0, 0);
        SCHED0; FENCE; BAR;

        LD_B8(1);
        if (g + 2 < NT) STAGE_A(0, g + 2, pb);
        FENCE; BAR; LGKM0; SCHED0;
        MM8(0, 1);
        SCHED0; FENCE; BAR;

        LD_A8(1);
        if (g + 2 < NT) STAGE_B(1, g + 2, pb);
        FENCE; BAR; LGKM0; SCHED0;
        MM8(1, 0);
        SCHED0; FENCE; BAR;

        if (g + 2 < NT) STAGE_B(0, g + 2, pb);
        if (g < NT - 2) {
            asm volatile("s_waitcnt vmcnt(6)" ::: "memory");
        } else if (g == NT - 2) {
            asm volatile("s_waitcnt vmcnt(0)" ::: "memory");
        }
        FENCE; BAR; LGKM0; SCHED0;
        MM8(1, 1);
        SCHED0; FENCE; BAR;
    }
    asm volatile("s_waitcnt vmcnt(0)" ::: "memory");

    float bb[4];
#pragma unroll
    for (int j = 0; j < 4; ++j) bb[j] = bias[bn0 + wn * 64 + j * 16 + l15];
#pragma unroll
    for (int i = 0; i < 8; ++i) {
        int rowb = bm0 + wm * 128 + i * 16 + quad * 4;
#pragma unroll
        for (int r = 0; r < 4; ++r) {
            size_t rb = (size_t)(rowb + r) * N_DIM + bn0 + wn * 64 + l15;
#pragma unroll
            for (int j = 0; j < 4; ++j)
                outBf[rb + j * 16] = f2bf(acc[i][j][r] + bb[j]);
        }
    }

    {
        const int q4 = quad * 4;
        const int bchk = ((bm0 >> 10) * NCHUNK) + ((bm0 >> 7) & 7) + wm;
        float* cdst = carry + (size_t)bchk * N_DIM + bn0 + wn * 64;
#pragma unroll
        for (int j = 0; j < 4; ++j) {
            float a  = decay[bn0 + wn * 64 + j * 16 + l15];
            float a2 = a * a, a4 = a2 * a2, a8 = a4 * a4, a16 = a8 * a8;
            float S = 0.f;
#pragma unroll
            for (int r = 0; r < 4; ++r) {
                int n = 15 - q4 - r;
                float w = 1.f;
                w *= (n & 1) ? a  : 1.f;
                w *= (n & 2) ? a2 : 1.f;
                w *= (n & 4) ? a4 : 1.f;
                w *= (n & 8) ? a8 : 1.f;
#pragma unroll
                for (int ii = 0; ii < 8; ++ii) {
                    S = fmaf(w, acc[7 - ii][j][r], S);
                    w *= a16;
                }
            }
            S += __shfl_xor(S, 16, 64);
            S += __shfl_xor(S, 32, 64);
            float a32 = a16 * a16, a64 = a32 * a32, a128 = a64 * a64;
            float cv = (1.f - a) * S + bb[j] * (1.f - a128);
            if (quad == 0) cdst[j * 16 + l15] = cv;
        }
    }
#undef STAGE_A
}

// ---------------------------------------------------------------------------
// Scan-apply: seed from carries, re-scan own chunk from bf16 C, write f32.
// ---------------------------------------------------------------------------
__global__ __launch_bounds__(256) void scan_apply2(
    const uint32* __restrict__ cur32,         // [M, N/2] (bf16 pairs)
    const float* __restrict__ decay,
    const float* __restrict__ carry,          // [B, NCHUNK, N]
    float* __restrict__ out) {                // [M, N] fp32
    int tid   = blockIdx.x * 256 + threadIdx.x;
    int o2    = tid & 511;
    int chunk = (tid >> 9) & (NCHUNK - 1);
    int b     = tid >> 12;
    int o     = o2 * 2;
    size_t base = ((size_t)b * T_DIM + (size_t)chunk * CHUNK_T) * (N_DIM / 2) + o2;
    float2 a2 = *(const float2*)&decay[o];
    float a0 = a2.x, a1 = a2.y;
    float c0 = 1.f - a0, c1 = 1.f - a1;

    float A0 = a0, A1 = a1;
#pragma unroll
    for (int i = 0; i < 7; ++i) { A0 *= A0; A1 *= A1; }   // a^128

    float u0 = 0.f, u1 = 0.f;
    const float* cb = carry + (size_t)b * NCHUNK * N_DIM + o;
    for (int i = 0; i < chunk; ++i) {         // wave-uniform trip count
        float2 cv = *(const float2*)&cb[(size_t)i * N_DIM];
        u0 = cv.x + A0 * u0;
        u1 = cv.y + A1 * u1;
    }

    float2* out2 = (float2*)out;
    size_t obase = ((size_t)b * T_DIM + (size_t)chunk * CHUNK_T) * (N_DIM / 2) + o2;
    for (int t0 = 0; t0 < CHUNK_T; t0 += 32) {
        uint32 x[32];
#pragma unroll
        for (int k = 0; k < 32; ++k)
            x[k] = cur32[base + (size_t)(t0 + k) * (N_DIM / 2)];
#pragma unroll
        for (int k = 0; k < 32; ++k) {
            float lo = __uint_as_float(x[k] << 16);
            float hi = __uint_as_float(x[k] & 0xffff0000u);
            u0 = a0 * u0 + c0 * lo;
            u1 = a1 * u1 + c1 * hi;
            out2[obase + (size_t)(t0 + k) * (N_DIM / 2)] = (float2){u0, u1};
        }
    }
}

// ---------------------------------------------------------------------------
// Fallbacks (only used if workspace too small for the bf16 path)
// ---------------------------------------------------------------------------
__global__ void scan_f32_inplace(float* __restrict__ buf,
                                 const float* __restrict__ decay) {
    int tid = blockIdx.x * 64 + threadIdx.x;
    int o = tid & (N_DIM - 1);
    size_t base = ((size_t)(tid >> 10) << 20) + o;
    float a = decay[o];
    float c = 1.f - a;
    float u = 0.f;
    for (int t0 = 0; t0 < 1024; t0 += 16) {
        float x[16];
#pragma unroll
        for (int k = 0; k < 16; ++k)
            x[k] = buf[base + (size_t)(t0 + k) * N_DIM];
#pragma unroll
        for (int k = 0; k < 16; ++k) {
            u = a * u + c * x[k];
            buf[base + (size_t)(t0 + k) * N_DIM] = u;
        }
    }
}

__global__ __launch_bounds__(256) void gemm_mfma(
    const unsigned short* __restrict__ A,
    const unsigned short* __restrict__ Bw,
    const float* __restrict__ bias,
    unsigned short* outBf,
    float* outF) {
    __shared__ unsigned short As[128 * 64];
    __shared__ unsigned short Bs[128 * 64];

    const int tid  = threadIdx.x;
    const int lane = tid & 63;
    const int wid  = tid >> 6;
    const int l15  = lane & 15;
    const int quad = lane >> 4;
    const int wm   = wid >> 1;
    const int wn   = wid & 1;

    const int L    = blockIdx.y * gridDim.x + blockIdx.x;
    const int xcd  = L & 7;
    const int s    = L >> 3;
    const int bn0  = (s & 7) * 128;
    const int bm0  = (xcd * 32 + (s >> 3)) * 128;

    floatx4 acc[4][4];
#pragma unroll
    for (int i = 0; i < 4; ++i)
#pragma unroll
        for (int j = 0; j < 4; ++j)
            acc[i][j] = (floatx4){0.f, 0.f, 0.f, 0.f};

    for (int kt = 0; kt < K_DIM / 64; ++kt) {
        const int k0 = kt * 64;
#pragma unroll
        for (int q = 0; q < 4; ++q) {
            int slot = q * 256 + tid;
            int row  = slot >> 3;
            int chq  = slot & 7;
            int scq  = chq ^ (row & 7);
            async_load16(A + (size_t)(bm0 + row) * K_DIM + k0 + scq * 8,
                         &As[(q * 256 + wid * 64) * 8]);
        }
#pragma unroll
        for (int q = 0; q < 4; ++q) {
            int slot = q * 256 + tid;
            int row  = slot >> 3;
            int chq  = slot & 7;
            int scq  = chq ^ (row & 7);
            async_load16(Bw + (size_t)(bn0 + row) * K_DIM + k0 + scq * 8,
                         &Bs[(q * 256 + wid * 64) * 8]);
        }
        __syncthreads();

#pragma unroll
        for (int ks = 0; ks < 2; ++ks) {
            short8 af[4], bfr[4];
#pragma unroll
            for (int i = 0; i < 4; ++i) {
                int r = wm * 64 + i * 16 + l15;
                int c = ks * 4 + quad;
                af[i] = *(const short8*)&As[r * 64 + ((c ^ (r & 7)) * 8)];
            }
#pragma unroll
            for (int j = 0; j < 4; ++j) {
                int r = wn * 64 + j * 16 + l15;
                int c = ks * 4 + quad;
                bfr[j] = *(const short8*)&Bs[r * 64 + ((c ^ (r & 7)) * 8)];
            }
#pragma unroll
            for (int i = 0; i < 4; ++i)
#pragma unroll
                for (int j = 0; j < 4; ++j)
                    acc[i][j] = __builtin_amdgcn_mfma_f32_16x16x32_bf16(
                        af[i], bfr[j], acc[i][j], 0, 0, 0);
        }
        __syncthreads();
    }

#pragma unroll
    for (int j = 0; j < 4; ++j) {
        int col = bn0 + wn * 64 + j * 16 + l15;
        float bb = bias[col];
#pragma unroll
        for (int i = 0; i < 4; ++i) {
            int rowb = bm0 + wm * 64 + i * 16 + quad * 4;
#pragma unroll
            for (int r = 0; r < 4; ++r) {
                float v = acc[i][j][r] + bb;
                size_t idx = (size_t)(rowb + r) * N_DIM + col;
                if (outBf) outBf[idx] = f2bf(v);
                else       outF[idx]  = v;
            }
        }
    }
}

__global__ void gemm_naive(const float* __restrict__ X, const float* __restrict__ W,
                           const float* __restrict__ bias, float* __restrict__ out) {
    __shared__ float As[16][17], Bs[16][17];
    int tx = threadIdx.x, ty = threadIdx.y;
    int m0 = blockIdx.y * 16, n0 = blockIdx.x * 16;
    float acc = 0.f;
    for (int k0 = 0; k0 < K_DIM; k0 += 16) {
        As[ty][tx] = X[(size_t)(m0 + ty) * K_DIM + k0 + tx];
        Bs[ty][tx] = W[(size_t)(n0 + ty) * K_DIM + k0 + tx];
        __syncthreads();
#pragma unroll
        for (int kk = 0; kk < 16; ++kk) acc += As[ty][kk] * Bs[tx][kk];
        __syncthreads();
    }
    out[(size_t)(m0 + ty) * N_DIM + n0 + tx] = acc + bias[n0 + tx];
}

// ---------------------------------------------------------------------------
extern "C" void kernel_launch(void* const* d_in, const int* in_sizes, int n_in,
                              void* d_out, int out_size, void* d_ws, size_t ws_size,
                              hipStream_t stream) {
    const float* X     = (const float*)d_in[0];  // [B,T,IN]  = [M,K]
    const float* Wt    = (const float*)d_in[1];  // [OUT,IN]  = [N,K]
    const float* bias  = (const float*)d_in[2];  // [OUT]
    const float* decay = (const float*)d_in[3];  // [OUT]
    float* out = (float*)d_out;                  // [B,T,OUT] = [M,N]

    // One-time LDS opt-ins (host-side, capture-safe).
    static bool fused_ok = [] {
        return hipFuncSetAttribute(reinterpret_cast<const void*>(gemm_fused2),
                                   hipFuncAttributeMaxDynamicSharedMemorySize,
                                   131072) == hipSuccess;
    }();
    static bool lds128_ok = [] {
        return hipFuncSetAttribute(reinterpret_cast<const void*>(gemm_8phase),
                                   hipFuncAttributeMaxDynamicSharedMemorySize,
                                   131072) == hipSuccess;
    }();

    const size_t A_bytes  = (size_t)M_DIM * K_DIM * 2;            // 64 MB
    const size_t W_bytes  = (size_t)N_DIM * K_DIM * 2;            // 2 MB
    const size_t C_bytes  = (size_t)M_DIM * N_DIM * 2;            // 64 MB
    const size_t cr_bytes = (size_t)B_DIM * NCHUNK * N_DIM * 4;   // 1 MB
    const size_t need_new  = W_bytes + C_bytes + cr_bytes;        // ~67 MB
    const size_t need_mid  = A_bytes + W_bytes;
    const size_t need_full = A_bytes + W_bytes + C_bytes + cr_bytes;
    const int scan_threads = B_DIM * NCHUNK * N_DIM / 2;          // 131072

    if (fused_ok && ws_size >= need_new) {
        unsigned short* Wbf = (unsigned short*)d_ws;
        unsigned short* Cbf = (unsigned short*)((char*)d_ws + W_bytes);
        float* carry = (float*)((char*)d_ws + W_bytes + C_bytes);
        cast_f32_bf16_x8<<<(N_DIM * K_DIM / 8 + 255) / 256, 256, 0, stream>>>(Wt, Wbf, N_DIM * K_DIM / 8);
        gemm_fused2<<<dim3(4, 128), 512, 131072, stream>>>(X, Wbf, bias, decay, Cbf, carry);
        scan_apply2<<<scan_threads / 256, 256, 0, stream>>>((const uint32*)Cbf, decay, carry, out);
    } else if (lds128_ok && ws_size >= need_full) {
        unsigned short* Abf = (unsigned short*)d_ws;
        unsigned short* Wbf = (unsigned short*)((char*)d_ws + A_bytes);
        unsigned short* Cbf = (unsigned short*)((char*)d_ws + A_bytes + W_bytes);
        float* carry = (float*)((char*)d_ws + A_bytes + W_bytes + C_bytes);
        cast_f32_bf16_x8<<<(M_DIM * K_DIM / 8 + 255) / 256, 256, 0, stream>>>(X, Abf, M_DIM * K_DIM / 8);
        cast_f32_bf16_x8<<<(N_DIM * K_DIM / 8 + 255) / 256, 256, 0, stream>>>(Wt, Wbf, N_DIM * K_DIM / 8);
        gemm_8phase<<<dim3(4, 128), 512, 131072, stream>>>(Abf, Wbf, bias, decay, Cbf, carry);
        scan_apply2<<<scan_threads / 256, 256, 0, stream>>>((const uint32*)Cbf, decay, carry, out);
    } else if (ws_size >= need_mid) {
        unsigned short* Abf = (unsigned short*)d_ws;
        unsigned short* Wbf = (unsigned short*)((char*)d_ws + A_bytes);
        cast_f32_bf16_x8<<<(M_DIM * K_DIM / 8 + 255) / 256, 256, 0, stream>>>(X, Abf, M_DIM * K_DIM / 8);
        cast_f32_bf16_x8<<<(N_DIM * K_DIM / 8 + 255) / 256, 256, 0, stream>>>(Wt, Wbf, N_DIM * K_DIM / 8);
        gemm_mfma<<<dim3(N_DIM / 128, M_DIM / 128), 256, 0, stream>>>(Abf, Wbf, bias, nullptr, out);
        scan_f32_inplace<<<512, 64, 0, stream>>>(out, decay);
    } else {
        gemm_naive<<<dim3(N_DIM / 16, M_DIM / 16), dim3(16, 16), 0, stream>>>(X, Wt, bias, out);
        scan_f32_inplace<<<512, 64, 0, stream>>>(out, decay);
    }
}

// Round 11
// 132.463 us; speedup vs baseline: 1.3194x; 1.0081x over previous
//
#include <hip/hip_runtime.h>

// Problem constants: B=32, T=1024, IN=1024, OUT=1024
// M = B*T = 32768, K = IN = 1024, N = OUT = 1024
#define M_DIM 32768
#define N_DIM 1024
#define K_DIM 1024
#define T_DIM 1024
#define B_DIM 32
#define NCHUNK 8
#define CHUNK_T 128   // T_DIM / NCHUNK

typedef unsigned int uint32;
typedef __attribute__((ext_vector_type(8))) short short8;       // 8 bf16 (MFMA A/B frag)
typedef __attribute__((ext_vector_type(8))) unsigned short ushort8v;
typedef __attribute__((ext_vector_type(4))) float floatx4;      // MFMA C/D frag + asm loads

__device__ __forceinline__ unsigned short f2bf(float f) {
    uint32 u = __float_as_uint(f);
    uint32 r = u + 0x7fffu + ((u >> 16) & 1u);
    return (unsigned short)(r >> 16);
}

__device__ __forceinline__ void async_load16(const void* g, void* s) {
    __builtin_amdgcn_global_load_lds(
        (const __attribute__((address_space(1))) void*)g,
        (__attribute__((address_space(3))) void*)s,
        16, 0, 0);
}

// 8 f32 -> short8 of bf16 via v_cvt_pk_bf16_f32 (RNE, same as f2bf).
// Operands are ext_vector elements (scalars) — NEVER HIP struct float4 in
// asm "v" operands (R4 lesson). Also: in-flight asm-load dest registers must
// never be spill candidates (R10 lesson) — keep VGPR use well under budget.
__device__ __forceinline__ short8 pk8(floatx4 a, floatx4 b) {
    union { short8 s; uint32 d[4]; } u;
    asm("v_cvt_pk_bf16_f32 %0, %1, %2" : "=v"(u.d[0]) : "v"(a[0]), "v"(a[1]));
    asm("v_cvt_pk_bf16_f32 %0, %1, %2" : "=v"(u.d[1]) : "v"(a[2]), "v"(a[3]));
    asm("v_cvt_pk_bf16_f32 %0, %1, %2" : "=v"(u.d[2]) : "v"(b[0]), "v"(b[1]));
    asm("v_cvt_pk_bf16_f32 %0, %1, %2" : "=v"(u.d[3]) : "v"(b[2]), "v"(b[3]));
    return u.s;
}

// ---- shared schedule macros ------------------------------------------------
#define FENCE  asm volatile("" ::: "memory")
#define BAR    __builtin_amdgcn_s_barrier()
#define LGKM0  asm volatile("s_waitcnt lgkmcnt(0)" ::: "memory")
#define SCHED0 __builtin_amdgcn_sched_barrier(0)
#define VMW(N) asm volatile("s_waitcnt vmcnt(" #N ")" ::: "memory")

// B half-tile JH of K-tile T -> buf PB (R2 pattern, measured conflict-free).
#define STAGE_B(JH, T, PB) do {                                              \
        size_t kof_ = (size_t)(T) * 64 + sc8;                                \
        _Pragma("unroll") for (int q_ = 0; q_ < 2; ++q_) {                   \
            int br_ = (q_ * 2 + (tid >> 8)) * 64 + (JH) * 32 + (t3 & 31);    \
            int dr_ = (q_ * 2 + (wid >> 2)) * 64 + (JH) * 32 + (wid & 3) * 8;\
            async_load16(Bw + (size_t)(bn0 + br_) * K_DIM + kof_,            \
                         smem + (PB) * 32768 + 16384 + dr_ * 64);            \
        } } while (0)

// Fragment loads (R2 pattern, measured conflict-free).
#define LD_A8(IH) do {                                                       \
        const unsigned short* As_ = smem + pb * 32768;                       \
        _Pragma("unroll") for (int ii = 0; ii < 4; ++ii) {                   \
            int r_ = wm * 128 + (IH) * 64 + ii * 16 + l15;                   \
            _Pragma("unroll") for (int ks = 0; ks < 2; ++ks) {               \
                int c_ = ks * 4 + quad;                                      \
                af[ii][ks] = *(const short8*)&As_[r_ * 64 +                  \
                                                 ((c_ ^ (l15 & 7)) * 8)];    \
            } } } while (0)
#define LD_B8(JH) do {                                                       \
        const unsigned short* Bs_ = smem + pb * 32768 + 16384;               \
        _Pragma("unroll") for (int jj = 0; jj < 2; ++jj) {                   \
            int r_ = wn * 64 + ((JH) * 2 + jj) * 16 + l15;                   \
            _Pragma("unroll") for (int ks = 0; ks < 2; ++ks) {               \
                int c_ = ks * 4 + quad;                                      \
                bfr[(JH) * 2 + jj][ks] = *(const short8*)&Bs_[r_ * 64 +      \
                                                 ((c_ ^ (l15 & 7)) * 8)];    \
            } } } while (0)
#define MM8(IH, JH) do {                                                     \
        __builtin_amdgcn_s_setprio(1);                                       \
        _Pragma("unroll") for (int ii = 0; ii < 4; ++ii)                     \
        _Pragma("unroll") for (int jj = 0; jj < 2; ++jj)                     \
        _Pragma("unroll") for (int ks = 0; ks < 2; ++ks)                     \
            acc[(IH) * 4 + ii][(JH) * 2 + jj] =                              \
                __builtin_amdgcn_mfma_f32_16x16x32_bf16(                     \
                    af[ii][ks], bfr[(JH) * 2 + jj][ks],                      \
                    acc[(IH) * 4 + ii][(JH) * 2 + jj], 0, 0, 0);             \
        __builtin_amdgcn_s_setprio(0);                                       \
    } while (0)

// A reg-staging (cast-fused). Slot P holds f32 pair for row quarter P.
// RULE (R8 crash): the read of ar[2P..] (AWRITE) must PRECEDE any AISSUE
// redefinition of the same slot in program order, and the old load must be
// vmcnt-drained before the read. Never leave an in-flight load's dest
// registers reader-less.
#define AISSUE(P, T) do {                                                    \
        const float* p_ = abase[P] + (T) * 64;                               \
        asm volatile("global_load_dwordx4 %0, %1, off"                       \
                     : "=&v"(ar[2 * (P)]) : "v"(p_));                        \
        asm volatile("global_load_dwordx4 %0, %1, off offset:16"             \
                     : "=&v"(ar[2 * (P) + 1]) : "v"(p_));                    \
    } while (0)
// Convert + swizzled ds_write into buf PBDST (content layout == DMA layout:
// LDS chunk position p of row r holds global chunk p ^ (r&7)).
#define AWRITE(P, PBDST) do {                                                \
        int row_ = (P) * 64 + (tid >> 3);                                    \
        int cs_  = (tid & 7) ^ (row_ & 7);                                   \
        *(short8*)&smem[(PBDST) * 32768 + row_ * 64 + cs_ * 8] =             \
            pk8(ar[2 * (P)], ar[2 * (P) + 1]);                               \
    } while (0)

// ---------------------------------------------------------------------------
// fp32 -> bf16 cast, 8 elems/thread (16B store). W (2 MB) on main path;
// A-cast only in fallback.
// ---------------------------------------------------------------------------
__global__ void cast_f32_bf16_x8(const float* __restrict__ src,
                                 unsigned short* __restrict__ dst, int n8) {
    int i = blockIdx.x * blockDim.x + threadIdx.x;
    if (i < n8) {
        const float4* s4 = (const float4*)src;
        float4 v0 = s4[(size_t)i * 2];
        float4 v1 = s4[(size_t)i * 2 + 1];
        ushort8v o;
        o[0] = f2bf(v0.x); o[1] = f2bf(v0.y); o[2] = f2bf(v0.z); o[3] = f2bf(v0.w);
        o[4] = f2bf(v1.x); o[5] = f2bf(v1.y); o[6] = f2bf(v1.z); o[7] = f2bf(v1.w);
        ((ushort8v*)dst)[i] = o;
    }
}

// ---------------------------------------------------------------------------
// MAIN GEMM: 8-phase 256x256/BK=64, A-cast fused via reg-staging.
// (R9-verified, 133.5us total. R10's dual-slot-set variant NaN'd: +64 VGPR
// pushed allocation past the 2-wave/SIMD budget and the compiler spilled
// in-flight asm-load dest registers — spills of asm-load dests read garbage.)
//
// Phase = {ds_reads; VMW(N); BAR; lgkm0; MFMA; AWRITE(P)->buf po;
//          AISSUE(P, g+2) [+STAGE_B]; BAR}.
// AWRITE after MFMA (hides ds_write latency: drained by NEXT phase's lgkm0,
// covered by a barrier + MFMA by then — fixes R5's 130us). AISSUE strictly
// AFTER AWRITE (read-before-redefine — fixes R8's register-clobber crash).
//
// vmcnt ledger (issues AFTER each phase's VMW; 12 ops/tile:
// p0:+2(a0) p1:+4(b0,a1) p2:+2(a2) p3:+4(b1,a3)):
//   entering each phase outstanding = 12; VMW = 10/8/10/8 drains exactly
//   {a0}/{b0,a1}/{a2}/{b1,a3} of tile g+1 -> AWRITE operands + B residency.
//   Outstanding never < 8. Prologue: VMW(4) [A(0)] -> AWRITE buf0 -> issue
//   tile 1 (12 ops) -> VMW(12) [B(0)]. Tail tile 14: 10/6/4/0 (no issues,
//   no redefs). Tile 15: compute only.
// Cross-wave: AWRITE at pP(g) drained by writer's lgkm0 at pP+1(g), read at
// pP(g+1) or later (>= 2 barriers). STAGE_B targets regions read >=1 barrier
// earlier (R2's proven plan).
// Carry epilogue: R7-verified in-register chunk-carry (replaces scan_carry2).
// ---------------------------------------------------------------------------
__global__ __launch_bounds__(512, 2) void gemm_fused2(
    const float* __restrict__ X32,          // [M, K] fp32
    const unsigned short* __restrict__ Bw,  // [N, K] bf16
    const float* __restrict__ bias,         // [N]
    const float* __restrict__ decay,        // [N]
    unsigned short* __restrict__ outBf,     // [M, N] bf16
    float* __restrict__ carry) {            // [B, NCHUNK, N]
    extern __shared__ __align__(16) unsigned short smem[];  // 131072 B

    const int tid  = threadIdx.x;
    const int lane = tid & 63;
    const int wid  = tid >> 6;      // 0..7
    const int l15  = lane & 15;
    const int quad = lane >> 4;
    const int wm   = wid >> 2;      // 0..1
    const int wn   = wid & 3;       // 0..3

    // XCD-aware remap: 512 blocks; xcd owns 16 M-panels, 4 N-tiles each.
    const int L   = blockIdx.y * gridDim.x + blockIdx.x;   // 0..511
    const int xcd = L & 7;
    const int s   = L >> 3;
    const int bn0 = (s & 3) * 256;
    const int bm0 = (xcd * 16 + (s >> 2)) * 256;

    const int t3  = tid >> 3;                               // 0..63
    const int sc8 = ((tid & 7) ^ (t3 & 7)) * 8;             // B-staging swizzle

    // A-source base per row-quarter (thread-fixed; +T*64 floats per K-tile).
    const float* abase[4];
#pragma unroll
    for (int p = 0; p < 4; ++p)
        abase[p] = X32 + (size_t)(bm0 + p * 64 + (tid >> 3)) * K_DIM + (tid & 7) * 8;

    floatx4 acc[8][4];
#pragma unroll
    for (int i = 0; i < 8; ++i)
#pragma unroll
        for (int j = 0; j < 4; ++j)
            acc[i][j] = (floatx4){0.f, 0.f, 0.f, 0.f};

    short8 af[4][2];
    short8 bfr[4][2];
    floatx4 ar[8];                   // in-flight A f32 (literal indices only)

    // Prologue: tile 0 loads (8 A + 4 B), drain A, write buf0; issue tile 1
    // in steady age-order (a0,b0,a1,a2,b1,a3); drain tile-0 B; publish.
    AISSUE(0, 0); AISSUE(1, 0); AISSUE(2, 0); AISSUE(3, 0);
    STAGE_B(0, 0, 0); STAGE_B(1, 0, 0);
    VMW(4); SCHED0;
    AWRITE(0, 0); AWRITE(1, 0); AWRITE(2, 0); AWRITE(3, 0);
    AISSUE(0, 1); STAGE_B(0, 1, 1); AISSUE(1, 1); AISSUE(2, 1);
    STAGE_B(1, 1, 1); AISSUE(3, 1);
    LGKM0; VMW(12); FENCE; BAR;

    // Main loop: tiles 0..13 (issue gens 2..15, all valid).
#define TILE_MAIN(G) do {                                                    \
        const int pb = (G) & 1;                                              \
        const int po = pb ^ 1;                                               \
        LD_A8(0); LD_B8(0);                                                  \
        VMW(10); FENCE; BAR; LGKM0; SCHED0;                                  \
        MM8(0, 0);                                                           \
        SCHED0; AWRITE(0, po); AISSUE(0, (G) + 2); FENCE; BAR;               \
        LD_B8(1);                                                            \
        VMW(8); FENCE; BAR; LGKM0; SCHED0;                                   \
        MM8(0, 1);                                                           \
        SCHED0; AWRITE(1, po); STAGE_B(0, (G) + 2, pb); AISSUE(1, (G) + 2);  \
        FENCE; BAR;                                                          \
        LD_A8(1);                                                            \
        VMW(10); FENCE; BAR; LGKM0; SCHED0;                                  \
        MM8(1, 0);                                                           \
        SCHED0; AWRITE(2, po); AISSUE(2, (G) + 2); FENCE; BAR;               \
        VMW(8); FENCE; BAR; LGKM0; SCHED0;                                   \
        MM8(1, 1);                                                           \
        SCHED0; AWRITE(3, po); STAGE_B(1, (G) + 2, pb); AISSUE(3, (G) + 2);  \
        FENCE; BAR;                                                          \
    } while (0)

    for (int g = 0; g < 14; ++g) TILE_MAIN(g);
#undef TILE_MAIN

    // Tile 14 (pb=0): no issues, no redefs; tail VMW 10/6/4/0; AWRITEs fill
    // tile 15 -> buf1.
    {
        const int pb = 0;
        LD_A8(0); LD_B8(0);
        VMW(10); FENCE; BAR; LGKM0; SCHED0;
        MM8(0, 0);
        SCHED0; AWRITE(0, 1); FENCE; BAR;
        LD_B8(1);
        VMW(6); FENCE; BAR; LGKM0; SCHED0;
        MM8(0, 1);
        SCHED0; AWRITE(1, 1); FENCE; BAR;
        LD_A8(1);
        VMW(4); FENCE; BAR; LGKM0; SCHED0;
        MM8(1, 0);
        SCHED0; AWRITE(2, 1); FENCE; BAR;
        VMW(0); FENCE; BAR; LGKM0; SCHED0;
        MM8(1, 1);
        SCHED0; AWRITE(3, 1); FENCE; BAR;
    }
    // Tile 15 (pb=1): compute only (vmcnt == 0).
    {
        const int pb = 1;
        LD_A8(0); LD_B8(0); FENCE; BAR; LGKM0; SCHED0; MM8(0, 0); SCHED0; FENCE; BAR;
        LD_B8(1);           FENCE; BAR; LGKM0; SCHED0; MM8(0, 1); SCHED0; FENCE; BAR;
        LD_A8(1);           FENCE; BAR; LGKM0; SCHED0; MM8(1, 0); SCHED0; FENCE; BAR;
                            FENCE; BAR; LGKM0; SCHED0; MM8(1, 1); SCHED0; FENCE; BAR;
    }

    // ---- C store (j innermost: full 128B lines, no write amplification) ----
    float bb[4];
#pragma unroll
    for (int j = 0; j < 4; ++j) bb[j] = bias[bn0 + wn * 64 + j * 16 + l15];
#pragma unroll
    for (int i = 0; i < 8; ++i) {
        int rowb = bm0 + wm * 128 + i * 16 + quad * 4;
#pragma unroll
        for (int r = 0; r < 4; ++r) {
            size_t rb = (size_t)(rowb + r) * N_DIM + bn0 + wn * 64 + l15;
#pragma unroll
            for (int j = 0; j < 4; ++j)
                outBf[rb + j * 16] = f2bf(acc[i][j][r] + bb[j]);
        }
    }

    // ---- fused carry epilogue (R7-verified; registers + shfl, no barriers) --
    {
        const int q4 = quad * 4;
        const int bchk = ((bm0 >> 10) * NCHUNK) + ((bm0 >> 7) & 7) + wm;
        float* cdst = carry + (size_t)bchk * N_DIM + bn0 + wn * 64;
#pragma unroll
        for (int j = 0; j < 4; ++j) {
            float a  = decay[bn0 + wn * 64 + j * 16 + l15];
            float a2 = a * a, a4 = a2 * a2, a8 = a4 * a4, a16 = a8 * a8;
            float S = 0.f;
#pragma unroll
            for (int r = 0; r < 4; ++r) {
                int n = 15 - q4 - r;                // seed exponent, 0..15
                float w = 1.f;
                w *= (n & 1) ? a  : 1.f;
                w *= (n & 2) ? a2 : 1.f;
                w *= (n & 4) ? a4 : 1.f;
                w *= (n & 8) ? a8 : 1.f;
#pragma unroll
                for (int ii = 0; ii < 8; ++ii) {
                    S = fmaf(w, acc[7 - ii][j][r], S);
                    w *= a16;
                }
            }
            S += __shfl_xor(S, 16, 64);
            S += __shfl_xor(S, 32, 64);
            float a32 = a16 * a16, a64 = a32 * a32, a128 = a64 * a64;
            float cv = (1.f - a) * S + bb[j] * (1.f - a128);
            if (quad == 0) cdst[j * 16 + l15] = cv;
        }
    }
}

// ---------------------------------------------------------------------------
// R7 8-phase bf16 GEMM + fused carry — fallback (needs pre-cast A).
// ---------------------------------------------------------------------------
__global__ __launch_bounds__(512, 2) void gemm_8phase(
    const unsigned short* __restrict__ A,   // [M, K] bf16
    const unsigned short* __restrict__ Bw,  // [N, K] bf16
    const float* __restrict__ bias,         // [N]
    const float* __restrict__ decay,        // [N]
    unsigned short* __restrict__ outBf,     // [M, N] bf16
    float* __restrict__ carry) {            // [B, NCHUNK, N]
    extern __shared__ __align__(16) unsigned short smem[];  // 131072 B

    const int tid  = threadIdx.x;
    const int lane = tid & 63;
    const int wid  = tid >> 6;
    const int l15  = lane & 15;
    const int quad = lane >> 4;
    const int wm   = wid >> 2;
    const int wn   = wid & 3;

    const int L   = blockIdx.y * gridDim.x + blockIdx.x;
    const int xcd = L & 7;
    const int s   = L >> 3;
    const int bn0 = (s & 3) * 256;
    const int bm0 = (xcd * 16 + (s >> 2)) * 256;

    const int t3  = tid >> 3;
    const int sc8 = ((tid & 7) ^ (t3 & 7)) * 8;

#define STAGE_A(IH, T, PB) do {                                              \
        size_t kof_ = (size_t)(T) * 64 + sc8;                                \
        _Pragma("unroll") for (int q_ = 0; q_ < 2; ++q_) {                   \
            int ar_ = q_ * 128 + (IH) * 64 + t3;                             \
            int dr_ = q_ * 128 + (IH) * 64 + wid * 8;                        \
            async_load16(A + (size_t)(bm0 + ar_) * K_DIM + kof_,             \
                         smem + (PB) * 32768 + dr_ * 64);                    \
        } } while (0)

    floatx4 acc[8][4];
#pragma unroll
    for (int i = 0; i < 8; ++i)
#pragma unroll
        for (int j = 0; j < 4; ++j)
            acc[i][j] = (floatx4){0.f, 0.f, 0.f, 0.f};

    short8 af[4][2];
    short8 bfr[4][2];

    const int NT = K_DIM / 64;   // 16

    STAGE_A(0, 0, 0); STAGE_A(1, 0, 0); STAGE_B(0, 0, 0); STAGE_B(1, 0, 0);
    STAGE_A(0, 1, 1); STAGE_B(1, 1, 1); STAGE_B(0, 1, 1);
    asm volatile("s_waitcnt vmcnt(6)" ::: "memory");
    FENCE; BAR;

    for (int g = 0; g < NT; ++g) {
        const int pb = g & 1;
        const int po = pb ^ 1;

        LD_A8(0); LD_B8(0);
        if (g + 1 < NT) STAGE_A(1, g + 1, po);
        FENCE; BAR; LGKM0; SCHED0;
        MM8(0, 0);
        SCHED0; FENCE; BAR;

        LD_B8(1);
        if (g + 2 < NT) STAGE_A(0, g + 2, pb);
        FENCE; BAR; LGKM0; SCHED0;
        MM8(0, 1);
        SCHED0; FENCE; BAR;

        LD_A8(1);
        if (g + 2 < NT) STAGE_B(1, g + 2, pb);
        FENCE; BAR; LGKM0; SCHED0;
        MM8(1, 0);
        SCHED0; FENCE; BAR;

        if (g + 2 < NT) STAGE_B(0, g + 2, pb);
        if (g < NT - 2) {
            asm volatile("s_waitcnt vmcnt(6)" ::: "memory");
        } else if (g == NT - 2) {
            asm volatile("s_waitcnt vmcnt(0)" ::: "memory");
        }
        FENCE; BAR; LGKM0; SCHED0;
        MM8(1, 1);
        SCHED0; FENCE; BAR;
    }
    asm volatile("s_waitcnt vmcnt(0)" ::: "memory");

    float bb[4];
#pragma unroll
    for (int j = 0; j < 4; ++j) bb[j] = bias[bn0 + wn * 64 + j * 16 + l15];
#pragma unroll
    for (int i = 0; i < 8; ++i) {
        int rowb = bm0 + wm * 128 + i * 16 + quad * 4;
#pragma unroll
        for (int r = 0; r < 4; ++r) {
            size_t rb = (size_t)(rowb + r) * N_DIM + bn0 + wn * 64 + l15;
#pragma unroll
            for (int j = 0; j < 4; ++j)
                outBf[rb + j * 16] = f2bf(acc[i][j][r] + bb[j]);
        }
    }

    {
        const int q4 = quad * 4;
        const int bchk = ((bm0 >> 10) * NCHUNK) + ((bm0 >> 7) & 7) + wm;
        float* cdst = carry + (size_t)bchk * N_DIM + bn0 + wn * 64;
#pragma unroll
        for (int j = 0; j < 4; ++j) {
            float a  = decay[bn0 + wn * 64 + j * 16 + l15];
            float a2 = a * a, a4 = a2 * a2, a8 = a4 * a4, a16 = a8 * a8;
            float S = 0.f;
#pragma unroll
            for (int r = 0; r < 4; ++r) {
                int n = 15 - q4 - r;
                float w = 1.f;
                w *= (n & 1) ? a  : 1.f;
                w *= (n & 2) ? a2 : 1.f;
                w *= (n & 4) ? a4 : 1.f;
                w *= (n & 8) ? a8 : 1.f;
#pragma unroll
                for (int ii = 0; ii < 8; ++ii) {
                    S = fmaf(w, acc[7 - ii][j][r], S);
                    w *= a16;
                }
            }
            S += __shfl_xor(S, 16, 64);
            S += __shfl_xor(S, 32, 64);
            float a32 = a16 * a16, a64 = a32 * a32, a128 = a64 * a64;
            float cv = (1.f - a) * S + bb[j] * (1.f - a128);
            if (quad == 0) cdst[j * 16 + l15] = cv;
        }
    }
#undef STAGE_A
}

// ---------------------------------------------------------------------------
// Scan-apply: seed from carries, re-scan own chunk from bf16 C, write f32.
// ---------------------------------------------------------------------------
__global__ __launch_bounds__(256) void scan_apply2(
    const uint32* __restrict__ cur32,         // [M, N/2] (bf16 pairs)
    const float* __restrict__ decay,
    const float* __restrict__ carry,          // [B, NCHUNK, N]
    float* __restrict__ out) {                // [M, N] fp32
    int tid   = blockIdx.x * 256 + threadIdx.x;
    int o2    = tid & 511;
    int chunk = (tid >> 9) & (NCHUNK - 1);
    int b     = tid >> 12;
    int o     = o2 * 2;
    size_t base = ((size_t)b * T_DIM + (size_t)chunk * CHUNK_T) * (N_DIM / 2) + o2;
    float2 a2 = *(const float2*)&decay[o];
    float a0 = a2.x, a1 = a2.y;
    float c0 = 1.f - a0, c1 = 1.f - a1;

    float A0 = a0, A1 = a1;
#pragma unroll
    for (int i = 0; i < 7; ++i) { A0 *= A0; A1 *= A1; }   // a^128

    float u0 = 0.f, u1 = 0.f;
    const float* cb = carry + (size_t)b * NCHUNK * N_DIM + o;
    for (int i = 0; i < chunk; ++i) {         // wave-uniform trip count
        float2 cv = *(const float2*)&cb[(size_t)i * N_DIM];
        u0 = cv.x + A0 * u0;
        u1 = cv.y + A1 * u1;
    }

    float2* out2 = (float2*)out;
    size_t obase = ((size_t)b * T_DIM + (size_t)chunk * CHUNK_T) * (N_DIM / 2) + o2;
    for (int t0 = 0; t0 < CHUNK_T; t0 += 32) {
        uint32 x[32];
#pragma unroll
        for (int k = 0; k < 32; ++k)
            x[k] = cur32[base + (size_t)(t0 + k) * (N_DIM / 2)];
#pragma unroll
        for (int k = 0; k < 32; ++k) {
            float lo = __uint_as_float(x[k] << 16);
            float hi = __uint_as_float(x[k] & 0xffff0000u);
            u0 = a0 * u0 + c0 * lo;
            u1 = a1 * u1 + c1 * hi;
            out2[obase + (size_t)(t0 + k) * (N_DIM / 2)] = (float2){u0, u1};
        }
    }
}

// ---------------------------------------------------------------------------
// Fallbacks (only used if workspace too small for the bf16 path)
// ---------------------------------------------------------------------------
__global__ void scan_f32_inplace(float* __restrict__ buf,
                                 const float* __restrict__ decay) {
    int tid = blockIdx.x * 64 + threadIdx.x;
    int o = tid & (N_DIM - 1);
    size_t base = ((size_t)(tid >> 10) << 20) + o;
    float a = decay[o];
    float c = 1.f - a;
    float u = 0.f;
    for (int t0 = 0; t0 < 1024; t0 += 16) {
        float x[16];
#pragma unroll
        for (int k = 0; k < 16; ++k)
            x[k] = buf[base + (size_t)(t0 + k) * N_DIM];
#pragma unroll
        for (int k = 0; k < 16; ++k) {
            u = a * u + c * x[k];
            buf[base + (size_t)(t0 + k) * N_DIM] = u;
        }
    }
}

__global__ __launch_bounds__(256) void gemm_mfma(
    const unsigned short* __restrict__ A,
    const unsigned short* __restrict__ Bw,
    const float* __restrict__ bias,
    unsigned short* outBf,
    float* outF) {
    __shared__ unsigned short As[128 * 64];
    __shared__ unsigned short Bs[128 * 64];

    const int tid  = threadIdx.x;
    const int lane = tid & 63;
    const int wid  = tid >> 6;
    const int l15  = lane & 15;
    const int quad = lane >> 4;
    const int wm   = wid >> 1;
    const int wn   = wid & 1;

    const int L    = blockIdx.y * gridDim.x + blockIdx.x;
    const int xcd  = L & 7;
    const int s    = L >> 3;
    const int bn0  = (s & 7) * 128;
    const int bm0  = (xcd * 32 + (s >> 3)) * 128;

    floatx4 acc[4][4];
#pragma unroll
    for (int i = 0; i < 4; ++i)
#pragma unroll
        for (int j = 0; j < 4; ++j)
            acc[i][j] = (floatx4){0.f, 0.f, 0.f, 0.f};

    for (int kt = 0; kt < K_DIM / 64; ++kt) {
        const int k0 = kt * 64;
#pragma unroll
        for (int q = 0; q < 4; ++q) {
            int slot = q * 256 + tid;
            int row  = slot >> 3;
            int chq  = slot & 7;
            int scq  = chq ^ (row & 7);
            async_load16(A + (size_t)(bm0 + row) * K_DIM + k0 + scq * 8,
                         &As[(q * 256 + wid * 64) * 8]);
        }
#pragma unroll
        for (int q = 0; q < 4; ++q) {
            int slot = q * 256 + tid;
            int row  = slot >> 3;
            int chq  = slot & 7;
            int scq  = chq ^ (row & 7);
            async_load16(Bw + (size_t)(bn0 + row) * K_DIM + k0 + scq * 8,
                         &Bs[(q * 256 + wid * 64) * 8]);
        }
        __syncthreads();

#pragma unroll
        for (int ks = 0; ks < 2; ++ks) {
            short8 af[4], bfr[4];
#pragma unroll
            for (int i = 0; i < 4; ++i) {
                int r = wm * 64 + i * 16 + l15;
                int c = ks * 4 + quad;
                af[i] = *(const short8*)&As[r * 64 + ((c ^ (r & 7)) * 8)];
            }
#pragma unroll
            for (int j = 0; j < 4; ++j) {
                int r = wn * 64 + j * 16 + l15;
                int c = ks * 4 + quad;
                bfr[j] = *(const short8*)&Bs[r * 64 + ((c ^ (r & 7)) * 8)];
            }
#pragma unroll
            for (int i = 0; i < 4; ++i)
#pragma unroll
                for (int j = 0; j < 4; ++j)
                    acc[i][j] = __builtin_amdgcn_mfma_f32_16x16x32_bf16(
                        af[i], bfr[j], acc[i][j], 0, 0, 0);
        }
        __syncthreads();
    }

#pragma unroll
    for (int j = 0; j < 4; ++j) {
        int col = bn0 + wn * 64 + j * 16 + l15;
        float bb = bias[col];
#pragma unroll
        for (int i = 0; i < 4; ++i) {
            int rowb = bm0 + wm * 64 + i * 16 + quad * 4;
#pragma unroll
            for (int r = 0; r < 4; ++r) {
                float v = acc[i][j][r] + bb;
                size_t idx = (size_t)(rowb + r) * N_DIM + col;
                if (outBf) outBf[idx] = f2bf(v);
                else       outF[idx]  = v;
            }
        }
    }
}

__global__ void gemm_naive(const float* __restrict__ X, const float* __restrict__ W,
                           const float* __restrict__ bias, float* __restrict__ out) {
    __shared__ float As[16][17], Bs[16][17];
    int tx = threadIdx.x, ty = threadIdx.y;
    int m0 = blockIdx.y * 16, n0 = blockIdx.x * 16;
    float acc = 0.f;
    for (int k0 = 0; k0 < K_DIM; k0 += 16) {
        As[ty][tx] = X[(size_t)(m0 + ty) * K_DIM + k0 + tx];
        Bs[ty][tx] = W[(size_t)(n0 + ty) * K_DIM + k0 + tx];
        __syncthreads();
#pragma unroll
        for (int kk = 0; kk < 16; ++kk) acc += As[ty][kk] * Bs[tx][kk];
        __syncthreads();
    }
    out[(size_t)(m0 + ty) * N_DIM + n0 + tx] = acc + bias[n0 + tx];
}

// ---------------------------------------------------------------------------
extern "C" void kernel_launch(void* const* d_in, const int* in_sizes, int n_in,
                              void* d_out, int out_size, void* d_ws, size_t ws_size,
                              hipStream_t stream) {
    const float* X     = (const float*)d_in[0];  // [B,T,IN]  = [M,K]
    const float* Wt    = (const float*)d_in[1];  // [OUT,IN]  = [N,K]
    const float* bias  = (const float*)d_in[2];  // [OUT]
    const float* decay = (const float*)d_in[3];  // [OUT]
    float* out = (float*)d_out;                  // [B,T,OUT] = [M,N]

    // One-time LDS opt-ins (host-side, capture-safe).
    static bool fused_ok = [] {
        return hipFuncSetAttribute(reinterpret_cast<const void*>(gemm_fused2),
                                   hipFuncAttributeMaxDynamicSharedMemorySize,
                                   131072) == hipSuccess;
    }();
    static bool lds128_ok = [] {
        return hipFuncSetAttribute(reinterpret_cast<const void*>(gemm_8phase),
                                   hipFuncAttributeMaxDynamicSharedMemorySize,
                                   131072) == hipSuccess;
    }();

    const size_t A_bytes  = (size_t)M_DIM * K_DIM * 2;            // 64 MB
    const size_t W_bytes  = (size_t)N_DIM * K_DIM * 2;            // 2 MB
    const size_t C_bytes  = (size_t)M_DIM * N_DIM * 2;            // 64 MB
    const size_t cr_bytes = (size_t)B_DIM * NCHUNK * N_DIM * 4;   // 1 MB
    const size_t need_new  = W_bytes + C_bytes + cr_bytes;        // ~67 MB
    const size_t need_mid  = A_bytes + W_bytes;
    const size_t need_full = A_bytes + W_bytes + C_bytes + cr_bytes;
    const int scan_threads = B_DIM * NCHUNK * N_DIM / 2;          // 131072

    if (fused_ok && ws_size >= need_new) {
        unsigned short* Wbf = (unsigned short*)d_ws;
        unsigned short* Cbf = (unsigned short*)((char*)d_ws + W_bytes);
        float* carry = (float*)((char*)d_ws + W_bytes + C_bytes);
        cast_f32_bf16_x8<<<(N_DIM * K_DIM / 8 + 255) / 256, 256, 0, stream>>>(Wt, Wbf, N_DIM * K_DIM / 8);
        gemm_fused2<<<dim3(4, 128), 512, 131072, stream>>>(X, Wbf, bias, decay, Cbf, carry);
        scan_apply2<<<scan_threads / 256, 256, 0, stream>>>((const uint32*)Cbf, decay, carry, out);
    } else if (lds128_ok && ws_size >= need_full) {
        unsigned short* Abf = (unsigned short*)d_ws;
        unsigned short* Wbf = (unsigned short*)((char*)d_ws + A_bytes);
        unsigned short* Cbf = (unsigned short*)((char*)d_ws + A_bytes + W_bytes);
        float* carry = (float*)((char*)d_ws + A_bytes + W_bytes + C_bytes);
        cast_f32_bf16_x8<<<(M_DIM * K_DIM / 8 + 255) / 256, 256, 0, stream>>>(X, Abf, M_DIM * K_DIM / 8);
        cast_f32_bf16_x8<<<(N_DIM * K_DIM / 8 + 255) / 256, 256, 0, stream>>>(Wt, Wbf, N_DIM * K_DIM / 8);
        gemm_8phase<<<dim3(4, 128), 512, 131072, stream>>>(Abf, Wbf, bias, decay, Cbf, carry);
        scan_apply2<<<scan_threads / 256, 256, 0, stream>>>((const uint32*)Cbf, decay, carry, out);
    } else if (ws_size >= need_mid) {
        unsigned short* Abf = (unsigned short*)d_ws;
        unsigned short* Wbf = (unsigned short*)((char*)d_ws + A_bytes);
        cast_f32_bf16_x8<<<(M_DIM * K_DIM / 8 + 255) / 256, 256, 0, stream>>>(X, Abf, M_DIM * K_DIM / 8);
        cast_f32_bf16_x8<<<(N_DIM * K_DIM / 8 + 255) / 256, 256, 0, stream>>>(Wt, Wbf, N_DIM * K_DIM / 8);
        gemm_mfma<<<dim3(N_DIM / 128, M_DIM / 128), 256, 0, stream>>>(Abf, Wbf, bias, nullptr, out);
        scan_f32_inplace<<<512, 64, 0, stream>>>(out, decay);
    } else {
        gemm_naive<<<dim3(N_DIM / 16, M_DIM / 16), dim3(16, 16), 0, stream>>>(X, Wt, bias, out);
        scan_f32_inplace<<<512, 64, 0, stream>>>(out, decay);
    }
}

// Round 12
// 131.421 us; speedup vs baseline: 1.3298x; 1.0079x over previous
//
#include <hip/hip_runtime.h>

// Problem constants: B=32, T=1024, IN=1024, OUT=1024
// M = B*T = 32768, K = IN = 1024, N = OUT = 1024
#define M_DIM 32768
#define N_DIM 1024
#define K_DIM 1024
#define T_DIM 1024
#define B_DIM 32
#define NCHUNK 8
#define CHUNK_T 128   // T_DIM / NCHUNK

typedef unsigned int uint32;
typedef __attribute__((ext_vector_type(8))) short short8;       // 8 bf16 (MFMA A/B frag)
typedef __attribute__((ext_vector_type(8))) unsigned short ushort8v;
typedef __attribute__((ext_vector_type(4))) float floatx4;      // MFMA C/D frag + asm loads

__device__ __forceinline__ unsigned short f2bf(float f) {
    uint32 u = __float_as_uint(f);
    uint32 r = u + 0x7fffu + ((u >> 16) & 1u);
    return (unsigned short)(r >> 16);
}

__device__ __forceinline__ void async_load16(const void* g, void* s) {
    __builtin_amdgcn_global_load_lds(
        (const __attribute__((address_space(1))) void*)g,
        (__attribute__((address_space(3))) void*)s,
        16, 0, 0);
}

// 8 f32 -> short8 of bf16 via v_cvt_pk_bf16_f32 (RNE, same as f2bf).
// Operands are ext_vector elements (scalars) — NEVER HIP struct float4 in
// asm "v" operands (R4 lesson). Also: in-flight asm-load dest registers must
// never be spill candidates (R10 lesson) — keep VGPR use well under budget.
__device__ __forceinline__ short8 pk8(floatx4 a, floatx4 b) {
    union { short8 s; uint32 d[4]; } u;
    asm("v_cvt_pk_bf16_f32 %0, %1, %2" : "=v"(u.d[0]) : "v"(a[0]), "v"(a[1]));
    asm("v_cvt_pk_bf16_f32 %0, %1, %2" : "=v"(u.d[1]) : "v"(a[2]), "v"(a[3]));
    asm("v_cvt_pk_bf16_f32 %0, %1, %2" : "=v"(u.d[2]) : "v"(b[0]), "v"(b[1]));
    asm("v_cvt_pk_bf16_f32 %0, %1, %2" : "=v"(u.d[3]) : "v"(b[2]), "v"(b[3]));
    return u.s;
}

// ---- shared schedule macros ------------------------------------------------
#define FENCE  asm volatile("" ::: "memory")
#define BAR    __builtin_amdgcn_s_barrier()
#define LGKM0  asm volatile("s_waitcnt lgkmcnt(0)" ::: "memory")
#define SCHED0 __builtin_amdgcn_sched_barrier(0)
#define VMW(N) asm volatile("s_waitcnt vmcnt(" #N ")" ::: "memory")

// B half-tile JH of K-tile T -> buf PB (R2 pattern, measured conflict-free).
#define STAGE_B(JH, T, PB) do {                                              \
        size_t kof_ = (size_t)(T) * 64 + sc8;                                \
        _Pragma("unroll") for (int q_ = 0; q_ < 2; ++q_) {                   \
            int br_ = (q_ * 2 + (tid >> 8)) * 64 + (JH) * 32 + (t3 & 31);    \
            int dr_ = (q_ * 2 + (wid >> 2)) * 64 + (JH) * 32 + (wid & 3) * 8;\
            async_load16(Bw + (size_t)(bn0 + br_) * K_DIM + kof_,            \
                         smem + (PB) * 32768 + 16384 + dr_ * 64);            \
        } } while (0)

// Fragment loads (R2 pattern, measured conflict-free).
#define LD_A8(IH) do {                                                       \
        const unsigned short* As_ = smem + pb * 32768;                       \
        _Pragma("unroll") for (int ii = 0; ii < 4; ++ii) {                   \
            int r_ = wm * 128 + (IH) * 64 + ii * 16 + l15;                   \
            _Pragma("unroll") for (int ks = 0; ks < 2; ++ks) {               \
                int c_ = ks * 4 + quad;                                      \
                af[ii][ks] = *(const short8*)&As_[r_ * 64 +                  \
                                                 ((c_ ^ (l15 & 7)) * 8)];    \
            } } } while (0)
#define LD_B8(JH) do {                                                       \
        const unsigned short* Bs_ = smem + pb * 32768 + 16384;               \
        _Pragma("unroll") for (int jj = 0; jj < 2; ++jj) {                   \
            int r_ = wn * 64 + ((JH) * 2 + jj) * 16 + l15;                   \
            _Pragma("unroll") for (int ks = 0; ks < 2; ++ks) {               \
                int c_ = ks * 4 + quad;                                      \
                bfr[(JH) * 2 + jj][ks] = *(const short8*)&Bs_[r_ * 64 +      \
                                                 ((c_ ^ (l15 & 7)) * 8)];    \
            } } } while (0)
#define MM8(IH, JH) do {                                                     \
        __builtin_amdgcn_s_setprio(1);                                       \
        _Pragma("unroll") for (int ii = 0; ii < 4; ++ii)                     \
        _Pragma("unroll") for (int jj = 0; jj < 2; ++jj)                     \
        _Pragma("unroll") for (int ks = 0; ks < 2; ++ks)                     \
            acc[(IH) * 4 + ii][(JH) * 2 + jj] =                              \
                __builtin_amdgcn_mfma_f32_16x16x32_bf16(                     \
                    af[ii][ks], bfr[(JH) * 2 + jj][ks],                      \
                    acc[(IH) * 4 + ii][(JH) * 2 + jj], 0, 0, 0);             \
        __builtin_amdgcn_s_setprio(0);                                       \
    } while (0)

// A reg-staging (cast-fused). Slot P holds f32 pair for row quarter P.
// RULE (R8 crash): the read of ar[2P..] (AWRITE) must PRECEDE any AISSUE
// redefinition of the same slot in program order, and the old load must be
// vmcnt-drained before the read. Never leave an in-flight load's dest
// registers reader-less.
#define AISSUE(P, T) do {                                                    \
        const float* p_ = abase[P] + (T) * 64;                               \
        asm volatile("global_load_dwordx4 %0, %1, off"                       \
                     : "=&v"(ar[2 * (P)]) : "v"(p_));                        \
        asm volatile("global_load_dwordx4 %0, %1, off offset:16"             \
                     : "=&v"(ar[2 * (P) + 1]) : "v"(p_));                    \
    } while (0)
// Convert + swizzled ds_write into buf PBDST (content layout == DMA layout:
// LDS chunk position p of row r holds global chunk p ^ (r&7)).
#define AWRITE(P, PBDST) do {                                                \
        int row_ = (P) * 64 + (tid >> 3);                                    \
        int cs_  = (tid & 7) ^ (row_ & 7);                                   \
        *(short8*)&smem[(PBDST) * 32768 + row_ * 64 + cs_ * 8] =             \
            pk8(ar[2 * (P)], ar[2 * (P) + 1]);                               \
    } while (0)

// ---------------------------------------------------------------------------
// fp32 -> bf16 cast, 8 elems/thread (16B store). W (2 MB) on main path;
// A-cast only in fallback.
// ---------------------------------------------------------------------------
__global__ void cast_f32_bf16_x8(const float* __restrict__ src,
                                 unsigned short* __restrict__ dst, int n8) {
    int i = blockIdx.x * blockDim.x + threadIdx.x;
    if (i < n8) {
        const float4* s4 = (const float4*)src;
        float4 v0 = s4[(size_t)i * 2];
        float4 v1 = s4[(size_t)i * 2 + 1];
        ushort8v o;
        o[0] = f2bf(v0.x); o[1] = f2bf(v0.y); o[2] = f2bf(v0.z); o[3] = f2bf(v0.w);
        o[4] = f2bf(v1.x); o[5] = f2bf(v1.y); o[6] = f2bf(v1.z); o[7] = f2bf(v1.w);
        ((ushort8v*)dst)[i] = o;
    }
}

// ---------------------------------------------------------------------------
// MAIN GEMM: 8-phase 256x256/BK=64, A-cast fused via reg-staging.
// (R9/R11-verified structure, 132.5us total.)
//
// Phase = {ds_reads; VMW(N); BAR; lgkm0; MFMA; AWRITE(P)->buf po;
//          AISSUE(P, g+2) [+STAGE_B]; BAR}.
// AWRITE after MFMA (hides ds_write latency). AISSUE strictly AFTER AWRITE
// (read-before-redefine — R8 lesson). Single ar[8] set (R10 lesson: dual
// sets spilled in-flight asm-load dests -> NaN).
//
// vmcnt ledger (issues AFTER each phase's VMW; 12 ops/tile:
// p0:+2(a0) p1:+4(b0,a1) p2:+2(a2) p3:+4(b1,a3)):
//   entering each phase outstanding = 12; VMW = 10/8/10/8 drains exactly
//   {a0}/{b0,a1}/{a2}/{b1,a3} of tile g+1 -> AWRITE operands + B residency.
//   Outstanding never < 8. Prologue: VMW(4) [A(0)] -> AWRITE buf0 -> issue
//   tile 1 (12 ops) -> VMW(12) [B(0)]. Tail tile 14: 10/6/4/0 (no issues,
//   no redefs). Tile 15: compute only.
// R12 change: LDS-staged vectorized C epilogue (R3-field-verified layout) —
// per-wave private 4KB region, 16 ds_write_b16 -> 2 ds_read_b128 ->
// 2 x 16B global stores per lane; lanes 0-7 cover a full 128B line.
// Carry epilogue: R7-verified in-register chunk-carry (replaces scan_carry2).
// ---------------------------------------------------------------------------
__global__ __launch_bounds__(512, 2) void gemm_fused2(
    const float* __restrict__ X32,          // [M, K] fp32
    const unsigned short* __restrict__ Bw,  // [N, K] bf16
    const float* __restrict__ bias,         // [N]
    const float* __restrict__ decay,        // [N]
    unsigned short* __restrict__ outBf,     // [M, N] bf16
    float* __restrict__ carry) {            // [B, NCHUNK, N]
    extern __shared__ __align__(16) unsigned short smem[];  // 131072 B

    const int tid  = threadIdx.x;
    const int lane = tid & 63;
    const int wid  = tid >> 6;      // 0..7
    const int l15  = lane & 15;
    const int quad = lane >> 4;
    const int wm   = wid >> 2;      // 0..1
    const int wn   = wid & 3;       // 0..3

    // XCD-aware remap: 512 blocks; xcd owns 16 M-panels, 4 N-tiles each.
    const int L   = blockIdx.y * gridDim.x + blockIdx.x;   // 0..511
    const int xcd = L & 7;
    const int s   = L >> 3;
    const int bn0 = (s & 3) * 256;
    const int bm0 = (xcd * 16 + (s >> 2)) * 256;

    const int t3  = tid >> 3;                               // 0..63
    const int sc8 = ((tid & 7) ^ (t3 & 7)) * 8;             // B-staging swizzle

    // A-source base per row-quarter (thread-fixed; +T*64 floats per K-tile).
    const float* abase[4];
#pragma unroll
    for (int p = 0; p < 4; ++p)
        abase[p] = X32 + (size_t)(bm0 + p * 64 + (tid >> 3)) * K_DIM + (tid & 7) * 8;

    floatx4 acc[8][4];
#pragma unroll
    for (int i = 0; i < 8; ++i)
#pragma unroll
        for (int j = 0; j < 4; ++j)
            acc[i][j] = (floatx4){0.f, 0.f, 0.f, 0.f};

    short8 af[4][2];
    short8 bfr[4][2];
    floatx4 ar[8];                   // in-flight A f32 (literal indices only)

    // Prologue: tile 0 loads (8 A + 4 B), drain A, write buf0; issue tile 1
    // in steady age-order (a0,b0,a1,a2,b1,a3); drain tile-0 B; publish.
    AISSUE(0, 0); AISSUE(1, 0); AISSUE(2, 0); AISSUE(3, 0);
    STAGE_B(0, 0, 0); STAGE_B(1, 0, 0);
    VMW(4); SCHED0;
    AWRITE(0, 0); AWRITE(1, 0); AWRITE(2, 0); AWRITE(3, 0);
    AISSUE(0, 1); STAGE_B(0, 1, 1); AISSUE(1, 1); AISSUE(2, 1);
    STAGE_B(1, 1, 1); AISSUE(3, 1);
    LGKM0; VMW(12); FENCE; BAR;

    // Main loop: tiles 0..13 (issue gens 2..15, all valid).
#define TILE_MAIN(G) do {                                                    \
        const int pb = (G) & 1;                                              \
        const int po = pb ^ 1;                                               \
        LD_A8(0); LD_B8(0);                                                  \
        VMW(10); FENCE; BAR; LGKM0; SCHED0;                                  \
        MM8(0, 0);                                                           \
        SCHED0; AWRITE(0, po); AISSUE(0, (G) + 2); FENCE; BAR;               \
        LD_B8(1);                                                            \
        VMW(8); FENCE; BAR; LGKM0; SCHED0;                                   \
        MM8(0, 1);                                                           \
        SCHED0; AWRITE(1, po); STAGE_B(0, (G) + 2, pb); AISSUE(1, (G) + 2);  \
        FENCE; BAR;                                                          \
        LD_A8(1);                                                            \
        VMW(10); FENCE; BAR; LGKM0; SCHED0;                                  \
        MM8(1, 0);                                                           \
        SCHED0; AWRITE(2, po); AISSUE(2, (G) + 2); FENCE; BAR;               \
        VMW(8); FENCE; BAR; LGKM0; SCHED0;                                   \
        MM8(1, 1);                                                           \
        SCHED0; AWRITE(3, po); STAGE_B(1, (G) + 2, pb); AISSUE(3, (G) + 2);  \
        FENCE; BAR;                                                          \
    } while (0)

    for (int g = 0; g < 14; ++g) TILE_MAIN(g);
#undef TILE_MAIN

    // Tile 14 (pb=0): no issues, no redefs; tail VMW 10/6/4/0; AWRITEs fill
    // tile 15 -> buf1.
    {
        const int pb = 0;
        LD_A8(0); LD_B8(0);
        VMW(10); FENCE; BAR; LGKM0; SCHED0;
        MM8(0, 0);
        SCHED0; AWRITE(0, 1); FENCE; BAR;
        LD_B8(1);
        VMW(6); FENCE; BAR; LGKM0; SCHED0;
        MM8(0, 1);
        SCHED0; AWRITE(1, 1); FENCE; BAR;
        LD_A8(1);
        VMW(4); FENCE; BAR; LGKM0; SCHED0;
        MM8(1, 0);
        SCHED0; AWRITE(2, 1); FENCE; BAR;
        VMW(0); FENCE; BAR; LGKM0; SCHED0;
        MM8(1, 1);
        SCHED0; AWRITE(3, 1); FENCE; BAR;
    }
    // Tile 15 (pb=1): compute only (vmcnt == 0).
    {
        const int pb = 1;
        LD_A8(0); LD_B8(0); FENCE; BAR; LGKM0; SCHED0; MM8(0, 0); SCHED0; FENCE; BAR;
        LD_B8(1);           FENCE; BAR; LGKM0; SCHED0; MM8(0, 1); SCHED0; FENCE; BAR;
        LD_A8(1);           FENCE; BAR; LGKM0; SCHED0; MM8(1, 0); SCHED0; FENCE; BAR;
                            FENCE; BAR; LGKM0; SCHED0; MM8(1, 1); SCHED0; FENCE; BAR;
    }

    // ---- C store: LDS-staged vectorized (R3-verified layout) ---------------
    // Per-wave private 4KB region (bufs dead after final barrier; no
    // cross-wave hazard — only intra-wave lgkm ordering needed).
    // eb[rr][cc] = C[bm0+wm*128+i*16+rr][bn0+wn*64+cc]; lane reads row
    // lane>>3, 16B at col (lane&7)*8 -> lanes 0-7 = one full 128B line.
    float bb[4];
#pragma unroll
    for (int j = 0; j < 4; ++j) bb[j] = bias[bn0 + wn * 64 + j * 16 + l15];
    {
        unsigned short* eb = smem + wid * 2048;
#pragma unroll
        for (int i = 0; i < 8; ++i) {
#pragma unroll
            for (int j = 0; j < 4; ++j)
#pragma unroll
                for (int r = 0; r < 4; ++r)
                    eb[(quad * 4 + r) * 64 + j * 16 + l15] =
                        f2bf(acc[i][j][r] + bb[j]);
            asm volatile("s_waitcnt lgkmcnt(0)" ::: "memory");
            short8 v0 = *(const short8*)&eb[lane * 8];         // rows 0..7
            short8 v1 = *(const short8*)&eb[512 + lane * 8];   // rows 8..15
            int rowg = bm0 + wm * 128 + i * 16 + (lane >> 3);
            int colg = bn0 + wn * 64 + (lane & 7) * 8;
            *(short8*)&outBf[(size_t)rowg * N_DIM + colg] = v0;
            *(short8*)&outBf[(size_t)(rowg + 8) * N_DIM + colg] = v1;
        }
    }

    // ---- fused carry epilogue (R7-verified; registers + shfl, no barriers) --
    {
        const int q4 = quad * 4;
        const int bchk = ((bm0 >> 10) * NCHUNK) + ((bm0 >> 7) & 7) + wm;
        float* cdst = carry + (size_t)bchk * N_DIM + bn0 + wn * 64;
#pragma unroll
        for (int j = 0; j < 4; ++j) {
            float a  = decay[bn0 + wn * 64 + j * 16 + l15];
            float a2 = a * a, a4 = a2 * a2, a8 = a4 * a4, a16 = a8 * a8;
            float S = 0.f;
#pragma unroll
            for (int r = 0; r < 4; ++r) {
                int n = 15 - q4 - r;                // seed exponent, 0..15
                float w = 1.f;
                w *= (n & 1) ? a  : 1.f;
                w *= (n & 2) ? a2 : 1.f;
                w *= (n & 4) ? a4 : 1.f;
                w *= (n & 8) ? a8 : 1.f;
#pragma unroll
                for (int ii = 0; ii < 8; ++ii) {
                    S = fmaf(w, acc[7 - ii][j][r], S);
                    w *= a16;
                }
            }
            S += __shfl_xor(S, 16, 64);
            S += __shfl_xor(S, 32, 64);
            float a32 = a16 * a16, a64 = a32 * a32, a128 = a64 * a64;
            float cv = (1.f - a) * S + bb[j] * (1.f - a128);
            if (quad == 0) cdst[j * 16 + l15] = cv;
        }
    }
}

// ---------------------------------------------------------------------------
// R7 8-phase bf16 GEMM + fused carry — fallback (needs pre-cast A).
// ---------------------------------------------------------------------------
__global__ __launch_bounds__(512, 2) void gemm_8phase(
    const unsigned short* __restrict__ A,   // [M, K] bf16
    const unsigned short* __restrict__ Bw,  // [N, K] bf16
    const float* __restrict__ bias,         // [N]
    const float* __restrict__ decay,        // [N]
    unsigned short* __restrict__ outBf,     // [M, N] bf16
    float* __restrict__ carry) {            // [B, NCHUNK, N]
    extern __shared__ __align__(16) unsigned short smem[];  // 131072 B

    const int tid  = threadIdx.x;
    const int lane = tid & 63;
    const int wid  = tid >> 6;
    const int l15  = lane & 15;
    const int quad = lane >> 4;
    const int wm   = wid >> 2;
    const int wn   = wid & 3;

    const int L   = blockIdx.y * gridDim.x + blockIdx.x;
    const int xcd = L & 7;
    const int s   = L >> 3;
    const int bn0 = (s & 3) * 256;
    const int bm0 = (xcd * 16 + (s >> 2)) * 256;

    const int t3  = tid >> 3;
    const int sc8 = ((tid & 7) ^ (t3 & 7)) * 8;

#define STAGE_A(IH, T, PB) do {                                              \
        size_t kof_ = (size_t)(T) * 64 + sc8;                                \
        _Pragma("unroll") for (int q_ = 0; q_ < 2; ++q_) {                   \
            int ar_ = q_ * 128 + (IH) * 64 + t3;                             \
            int dr_ = q_ * 128 + (IH) * 64 + wid * 8;                        \
            async_load16(A + (size_t)(bm0 + ar_) * K_DIM + kof_,             \
                         smem + (PB) * 32768 + dr_ * 64);                    \
        } } while (0)

    floatx4 acc[8][4];
#pragma unroll
    for (int i = 0; i < 8; ++i)
#pragma unroll
        for (int j = 0; j < 4; ++j)
            acc[i][j] = (floatx4){0.f, 0.f, 0.f, 0.f};

    short8 af[4][2];
    short8 bfr[4][2];

    const int NT = K_DIM / 64;   // 16

    STAGE_A(0, 0, 0); STAGE_A(1, 0, 0); STAGE_B(0, 0, 0); STAGE_B(1, 0, 0);
    STAGE_A(0, 1, 1); STAGE_B(1, 1, 1); STAGE_B(0, 1, 1);
    asm volatile("s_waitcnt vmcnt(6)" ::: "memory");
    FENCE; BAR;

    for (int g = 0; g < NT; ++g) {
        const int pb = g & 1;
        const int po = pb ^ 1;

        LD_A8(0); LD_B8(0);
        if (g + 1 < NT) STAGE_A(1, g + 1, po);
        FENCE; BAR; LGKM0; SCHED0;
        MM8(0, 0);
        SCHED0; FENCE; BAR;

        LD_B8(1);
        if (g + 2 < NT) STAGE_A(0, g + 2, pb);
        FENCE; BAR; LGKM0; SCHED0;
        MM8(0, 1);
        SCHED0; FENCE; BAR;

        LD_A8(1);
        if (g + 2 < NT) STAGE_B(1, g + 2, pb);
        FENCE; BAR; LGKM0; SCHED0;
        MM8(1, 0);
        SCHED0; FENCE; BAR;

        if (g + 2 < NT) STAGE_B(0, g + 2, pb);
        if (g < NT - 2) {
            asm volatile("s_waitcnt vmcnt(6)" ::: "memory");
        } else if (g == NT - 2) {
            asm volatile("s_waitcnt vmcnt(0)" ::: "memory");
        }
        FENCE; BAR; LGKM0; SCHED0;
        MM8(1, 1);
        SCHED0; FENCE; BAR;
    }
    asm volatile("s_waitcnt vmcnt(0)" ::: "memory");

    float bb[4];
#pragma unroll
    for (int j = 0; j < 4; ++j) bb[j] = bias[bn0 + wn * 64 + j * 16 + l15];
#pragma unroll
    for (int i = 0; i < 8; ++i) {
        int rowb = bm0 + wm * 128 + i * 16 + quad * 4;
#pragma unroll
        for (int r = 0; r < 4; ++r) {
            size_t rb = (size_t)(rowb + r) * N_DIM + bn0 + wn * 64 + l15;
#pragma unroll
            for (int j = 0; j < 4; ++j)
                outBf[rb + j * 16] = f2bf(acc[i][j][r] + bb[j]);
        }
    }

    {
        const int q4 = quad * 4;
        const int bchk = ((bm0 >> 10) * NCHUNK) + ((bm0 >> 7) & 7) + wm;
        float* cdst = carry + (size_t)bchk * N_DIM + bn0 + wn * 64;
#pragma unroll
        for (int j = 0; j < 4; ++j) {
            float a  = decay[bn0 + wn * 64 + j * 16 + l15];
            float a2 = a * a, a4 = a2 * a2, a8 = a4 * a4, a16 = a8 * a8;
            float S = 0.f;
#pragma unroll
            for (int r = 0; r < 4; ++r) {
                int n = 15 - q4 - r;
                float w = 1.f;
                w *= (n & 1) ? a  : 1.f;
                w *= (n & 2) ? a2 : 1.f;
                w *= (n & 4) ? a4 : 1.f;
                w *= (n & 8) ? a8 : 1.f;
#pragma unroll
                for (int ii = 0; ii < 8; ++ii) {
                    S = fmaf(w, acc[7 - ii][j][r], S);
                    w *= a16;
                }
            }
            S += __shfl_xor(S, 16, 64);
            S += __shfl_xor(S, 32, 64);
            float a32 = a16 * a16, a64 = a32 * a32, a128 = a64 * a64;
            float cv = (1.f - a) * S + bb[j] * (1.f - a128);
            if (quad == 0) cdst[j * 16 + l15] = cv;
        }
    }
#undef STAGE_A
}

// ---------------------------------------------------------------------------
// Scan-apply: seed from carries, re-scan own chunk from bf16 C, write f32.
// ---------------------------------------------------------------------------
__global__ __launch_bounds__(256) void scan_apply2(
    const uint32* __restrict__ cur32,         // [M, N/2] (bf16 pairs)
    const float* __restrict__ decay,
    const float* __restrict__ carry,          // [B, NCHUNK, N]
    float* __restrict__ out) {                // [M, N] fp32
    int tid   = blockIdx.x * 256 + threadIdx.x;
    int o2    = tid & 511;
    int chunk = (tid >> 9) & (NCHUNK - 1);
    int b     = tid >> 12;
    int o     = o2 * 2;
    size_t base = ((size_t)b * T_DIM + (size_t)chunk * CHUNK_T) * (N_DIM / 2) + o2;
    float2 a2 = *(const float2*)&decay[o];
    float a0 = a2.x, a1 = a2.y;
    float c0 = 1.f - a0, c1 = 1.f - a1;

    float A0 = a0, A1 = a1;
#pragma unroll
    for (int i = 0; i < 7; ++i) { A0 *= A0; A1 *= A1; }   // a^128

    float u0 = 0.f, u1 = 0.f;
    const float* cb = carry + (size_t)b * NCHUNK * N_DIM + o;
    for (int i = 0; i < chunk; ++i) {         // wave-uniform trip count
        float2 cv = *(const float2*)&cb[(size_t)i * N_DIM];
        u0 = cv.x + A0 * u0;
        u1 = cv.y + A1 * u1;
    }

    float2* out2 = (float2*)out;
    size_t obase = ((size_t)b * T_DIM + (size_t)chunk * CHUNK_T) * (N_DIM / 2) + o2;
    for (int t0 = 0; t0 < CHUNK_T; t0 += 32) {
        uint32 x[32];
#pragma unroll
        for (int k = 0; k < 32; ++k)
            x[k] = cur32[base + (size_t)(t0 + k) * (N_DIM / 2)];
#pragma unroll
        for (int k = 0; k < 32; ++k) {
            float lo = __uint_as_float(x[k] << 16);
            float hi = __uint_as_float(x[k] & 0xffff0000u);
            u0 = a0 * u0 + c0 * lo;
            u1 = a1 * u1 + c1 * hi;
            out2[obase + (size_t)(t0 + k) * (N_DIM / 2)] = (float2){u0, u1};
        }
    }
}

// ---------------------------------------------------------------------------
// Fallbacks (only used if workspace too small for the bf16 path)
// ---------------------------------------------------------------------------
__global__ void scan_f32_inplace(float* __restrict__ buf,
                                 const float* __restrict__ decay) {
    int tid = blockIdx.x * 64 + threadIdx.x;
    int o = tid & (N_DIM - 1);
    size_t base = ((size_t)(tid >> 10) << 20) + o;
    float a = decay[o];
    float c = 1.f - a;
    float u = 0.f;
    for (int t0 = 0; t0 < 1024; t0 += 16) {
        float x[16];
#pragma unroll
        for (int k = 0; k < 16; ++k)
            x[k] = buf[base + (size_t)(t0 + k) * N_DIM];
#pragma unroll
        for (int k = 0; k < 16; ++k) {
            u = a * u + c * x[k];
            buf[base + (size_t)(t0 + k) * N_DIM] = u;
        }
    }
}

__global__ __launch_bounds__(256) void gemm_mfma(
    const unsigned short* __restrict__ A,
    const unsigned short* __restrict__ Bw,
    const float* __restrict__ bias,
    unsigned short* outBf,
    float* outF) {
    __shared__ unsigned short As[128 * 64];
    __shared__ unsigned short Bs[128 * 64];

    const int tid  = threadIdx.x;
    const int lane = tid & 63;
    const int wid  = tid >> 6;
    const int l15  = lane & 15;
    const int quad = lane >> 4;
    const int wm   = wid >> 1;
    const int wn   = wid & 1;

    const int L    = blockIdx.y * gridDim.x + blockIdx.x;
    const int xcd  = L & 7;
    const int s    = L >> 3;
    const int bn0  = (s & 7) * 128;
    const int bm0  = (xcd * 32 + (s >> 3)) * 128;

    floatx4 acc[4][4];
#pragma unroll
    for (int i = 0; i < 4; ++i)
#pragma unroll
        for (int j = 0; j < 4; ++j)
            acc[i][j] = (floatx4){0.f, 0.f, 0.f, 0.f};

    for (int kt = 0; kt < K_DIM / 64; ++kt) {
        const int k0 = kt * 64;
#pragma unroll
        for (int q = 0; q < 4; ++q) {
            int slot = q * 256 + tid;
            int row  = slot >> 3;
            int chq  = slot & 7;
            int scq  = chq ^ (row & 7);
            async_load16(A + (size_t)(bm0 + row) * K_DIM + k0 + scq * 8,
                         &As[(q * 256 + wid * 64) * 8]);
        }
#pragma unroll
        for (int q = 0; q < 4; ++q) {
            int slot = q * 256 + tid;
            int row  = slot >> 3;
            int chq  = slot & 7;
            int scq  = chq ^ (row & 7);
            async_load16(Bw + (size_t)(bn0 + row) * K_DIM + k0 + scq * 8,
                         &Bs[(q * 256 + wid * 64) * 8]);
        }
        __syncthreads();

#pragma unroll
        for (int ks = 0; ks < 2; ++ks) {
            short8 af[4], bfr[4];
#pragma unroll
            for (int i = 0; i < 4; ++i) {
                int r = wm * 64 + i * 16 + l15;
                int c = ks * 4 + quad;
                af[i] = *(const short8*)&As[r * 64 + ((c ^ (r & 7)) * 8)];
            }
#pragma unroll
            for (int j = 0; j < 4; ++j) {
                int r = wn * 64 + j * 16 + l15;
                int c = ks * 4 + quad;
                bfr[j] = *(const short8*)&Bs[r * 64 + ((c ^ (r & 7)) * 8)];
            }
#pragma unroll
            for (int i = 0; i < 4; ++i)
#pragma unroll
                for (int j = 0; j < 4; ++j)
                    acc[i][j] = __builtin_amdgcn_mfma_f32_16x16x32_bf16(
                        af[i], bfr[j], acc[i][j], 0, 0, 0);
        }
        __syncthreads();
    }

#pragma unroll
    for (int j = 0; j < 4; ++j) {
        int col = bn0 + wn * 64 + j * 16 + l15;
        float bb = bias[col];
#pragma unroll
        for (int i = 0; i < 4; ++i) {
            int rowb = bm0 + wm * 64 + i * 16 + quad * 4;
#pragma unroll
            for (int r = 0; r < 4; ++r) {
                float v = acc[i][j][r] + bb;
                size_t idx = (size_t)(rowb + r) * N_DIM + col;
                if (outBf) outBf[idx] = f2bf(v);
                else       outF[idx]  = v;
            }
        }
    }
}

__global__ void gemm_naive(const float* __restrict__ X, const float* __restrict__ W,
                           const float* __restrict__ bias, float* __restrict__ out) {
    __shared__ float As[16][17], Bs[16][17];
    int tx = threadIdx.x, ty = threadIdx.y;
    int m0 = blockIdx.y * 16, n0 = blockIdx.x * 16;
    float acc = 0.f;
    for (int k0 = 0; k0 < K_DIM; k0 += 16) {
        As[ty][tx] = X[(size_t)(m0 + ty) * K_DIM + k0 + tx];
        Bs[ty][tx] = W[(size_t)(n0 + ty) * K_DIM + k0 + tx];
        __syncthreads();
#pragma unroll
        for (int kk = 0; kk < 16; ++kk) acc += As[ty][kk] * Bs[tx][kk];
        __syncthreads();
    }
    out[(size_t)(m0 + ty) * N_DIM + n0 + tx] = acc + bias[n0 + tx];
}

// ---------------------------------------------------------------------------
extern "C" void kernel_launch(void* const* d_in, const int* in_sizes, int n_in,
                              void* d_out, int out_size, void* d_ws, size_t ws_size,
                              hipStream_t stream) {
    const float* X     = (const float*)d_in[0];  // [B,T,IN]  = [M,K]
    const float* Wt    = (const float*)d_in[1];  // [OUT,IN]  = [N,K]
    const float* bias  = (const float*)d_in[2];  // [OUT]
    const float* decay = (const float*)d_in[3];  // [OUT]
    float* out = (float*)d_out;                  // [B,T,OUT] = [M,N]

    // One-time LDS opt-ins (host-side, capture-safe).
    static bool fused_ok = [] {
        return hipFuncSetAttribute(reinterpret_cast<const void*>(gemm_fused2),
                                   hipFuncAttributeMaxDynamicSharedMemorySize,
                                   131072) == hipSuccess;
    }();
    static bool lds128_ok = [] {
        return hipFuncSetAttribute(reinterpret_cast<const void*>(gemm_8phase),
                                   hipFuncAttributeMaxDynamicSharedMemorySize,
                                   131072) == hipSuccess;
    }();

    const size_t A_bytes  = (size_t)M_DIM * K_DIM * 2;            // 64 MB
    const size_t W_bytes  = (size_t)N_DIM * K_DIM * 2;            // 2 MB
    const size_t C_bytes  = (size_t)M_DIM * N_DIM * 2;            // 64 MB
    const size_t cr_bytes = (size_t)B_DIM * NCHUNK * N_DIM * 4;   // 1 MB
    const size_t need_new  = W_bytes + C_bytes + cr_bytes;        // ~67 MB
    const size_t need_mid  = A_bytes + W_bytes;
    const size_t need_full = A_bytes + W_bytes + C_bytes + cr_bytes;
    const int scan_threads = B_DIM * NCHUNK * N_DIM / 2;          // 131072

    if (fused_ok && ws_size >= need_new) {
        unsigned short* Wbf = (unsigned short*)d_ws;
        unsigned short* Cbf = (unsigned short*)((char*)d_ws + W_bytes);
        float* carry = (float*)((char*)d_ws + W_bytes + C_bytes);
        cast_f32_bf16_x8<<<(N_DIM * K_DIM / 8 + 255) / 256, 256, 0, stream>>>(Wt, Wbf, N_DIM * K_DIM / 8);
        gemm_fused2<<<dim3(4, 128), 512, 131072, stream>>>(X, Wbf, bias, decay, Cbf, carry);
        scan_apply2<<<scan_threads / 256, 256, 0, stream>>>((const uint32*)Cbf, decay, carry, out);
    } else if (lds128_ok && ws_size >= need_full) {
        unsigned short* Abf = (unsigned short*)d_ws;
        unsigned short* Wbf = (unsigned short*)((char*)d_ws + A_bytes);
        unsigned short* Cbf = (unsigned short*)((char*)d_ws + A_bytes + W_bytes);
        float* carry = (float*)((char*)d_ws + A_bytes + W_bytes + C_bytes);
        cast_f32_bf16_x8<<<(M_DIM * K_DIM / 8 + 255) / 256, 256, 0, stream>>>(X, Abf, M_DIM * K_DIM / 8);
        cast_f32_bf16_x8<<<(N_DIM * K_DIM / 8 + 255) / 256, 256, 0, stream>>>(Wt, Wbf, N_DIM * K_DIM / 8);
        gemm_8phase<<<dim3(4, 128), 512, 131072, stream>>>(Abf, Wbf, bias, decay, Cbf, carry);
        scan_apply2<<<scan_threads / 256, 256, 0, stream>>>((const uint32*)Cbf, decay, carry, out);
    } else if (ws_size >= need_mid) {
        unsigned short* Abf = (unsigned short*)d_ws;
        unsigned short* Wbf = (unsigned short*)((char*)d_ws + A_bytes);
        cast_f32_bf16_x8<<<(M_DIM * K_DIM / 8 + 255) / 256, 256, 0, stream>>>(X, Abf, M_DIM * K_DIM / 8);
        cast_f32_bf16_x8<<<(N_DIM * K_DIM / 8 + 255) / 256, 256, 0, stream>>>(Wt, Wbf, N_DIM * K_DIM / 8);
        gemm_mfma<<<dim3(N_DIM / 128, M_DIM / 128), 256, 0, stream>>>(Abf, Wbf, bias, nullptr, out);
        scan_f32_inplace<<<512, 64, 0, stream>>>(out, decay);
    } else {
        gemm_naive<<<dim3(N_DIM / 16, M_DIM / 16), dim3(16, 16), 0, stream>>>(X, Wt, bias, out);
        scan_f32_inplace<<<512, 64, 0, stream>>>(out, decay);
    }
}